// Round 14
// baseline (735.797 us; speedup 1.0000x reference)
//
#include <hip/hip_runtime.h>
#include <math.h>

typedef float f32x4 __attribute__((ext_vector_type(4)));
typedef short bf16x8 __attribute__((ext_vector_type(8)));
typedef unsigned short u16;
typedef unsigned int u32;

#define FLAG_STRIDE 16            // one u32 flag per 64B line
#define ACQ_BASE    8192          // 256 acquire-dummy lines (after 128*64 step flags)
#define EPOCH_BASE  8448          // 64 epoch lines
#define QCNT_BASE   8512          // 16 tile-queue lines
#define FLAG_WORDS  ((QCNT_BASE + 16) * FLAG_STRIDE)
#define NTILE       125           // 32000 / 256 proj n-tiles per chunk

__device__ __forceinline__ u16 f2bf(float f) {
    union { float f; unsigned u; } x; x.f = f;
    unsigned r = x.u + 0x7fff + ((x.u >> 16) & 1);   // RNE
    return (u16)(r >> 16);
}

// async global->LDS, 16B/lane. LDS dest wave-uniform base; HW adds lane*16. Global src per-lane.
__device__ __forceinline__ void gload_lds16(const u16* g, u16* l) {
    __builtin_amdgcn_global_load_lds(
        (const __attribute__((address_space(1))) void*)g,
        (__attribute__((address_space(3))) void*)l, 16, 0, 0);
}

// ================= prep: gather + bias concat + all transposes in ONE launch =================
__global__ __launch_bounds__(256) void prep(
    const int* __restrict__ sent, const float* __restrict__ emb, u16* __restrict__ xb,
    const float* __restrict__ bi, const float* __restrict__ bf_,
    const float* __restrict__ bo, const float* __restrict__ bc, float* __restrict__ b4,
    const float* __restrict__ Wi, const float* __restrict__ Wf,
    const float* __restrict__ Wo, const float* __restrict__ Wc, u16* __restrict__ wxt,
    const float* __restrict__ Whq, u16* __restrict__ whqt) {
    __shared__ float tile[32][33];
    const int bx = blockIdx.x, tid = threadIdx.x;
    if (bx < 1024) {                       // embedding gather, 2 rows/WG
        int row = bx * 2 + (tid >> 7);     // t*16+b
        int t = row >> 4, b = row & 15;
        int idx = sent[b * 128 + t];
        float4 v = ((const float4*)(emb + (size_t)idx * 512))[tid & 127];
        ushort4 s = { f2bf(v.x), f2bf(v.y), f2bf(v.z), f2bf(v.w) };
        ((ushort4*)(xb + (size_t)row * 512))[tid & 127] = s;
        return;
    }
    if (bx < 1040) {                       // b4
        int i = (bx - 1024) * 256 + tid;
        const float* p = (i < 1024) ? bi : (i < 2048) ? bf_ : (i < 3072) ? bo : bc;
        b4[i] = p[i & 1023];
        return;
    }
    const float* in; u16* out; int ldin, ldout, rt, ct;
    if (bx < 3088) {                       // 4x Wx: rows 0..512 of W_g[1536][1024]
        int q = bx - 1040, g = q >> 9, r = q & 511;
        in = (g == 0) ? Wi : (g == 1) ? Wf : (g == 2) ? Wo : Wc;
        ldin = 1024; out = wxt + (size_t)g * 1024 * 512; ldout = 512;
        rt = (r >> 5) * 32; ct = (r & 31) * 32;
    } else {                               // W_hq [1024][32000] -> whqt [32000][1024]
        int q = bx - 3088;
        in = Whq; ldin = 32000; out = whqt; ldout = 1024;
        rt = (q / 1000) * 32; ct = (q % 1000) * 32;
    }
    {
        int r = tid >> 3, cq = (tid & 7) * 4;
        float4 v = *(const float4*)(in + (size_t)(rt + r) * ldin + ct + cq);
        tile[r][cq] = v.x; tile[r][cq + 1] = v.y; tile[r][cq + 2] = v.z; tile[r][cq + 3] = v.w;
        __syncthreads();
        int c = tid >> 3, rq = (tid & 7) * 4;
        ushort4 s = { f2bf(tile[rq][c]), f2bf(tile[rq + 1][c]),
                      f2bf(tile[rq + 2][c]), f2bf(tile[rq + 3][c]) };
        *(ushort4*)(out + (size_t)(ct + c) * ldout + rt + rq) = s;
    }
}

// ================= xz GEMM: xz[M][4096] = xb[M][512](bf16) @ wxt[4096][512]^T + b4 =================
__global__ __launch_bounds__(256) void gemm_xz(
    const u16* __restrict__ A, const u16* __restrict__ Bt,
    const float* __restrict__ bias, float* __restrict__ C) {
    const int tid = threadIdx.x;
    const int l = tid & 63, w = tid >> 6;
    const int wr = w >> 1, wc = w & 1;
    const int m0 = blockIdx.x * 128, n0 = blockIdx.y * 128;
    const int K = 512;
    __shared__ __align__(16) u16 As[128 * 64];
    __shared__ __align__(16) u16 Bs[128 * 64];
    f32x4 acc[4][4];
    f32x4 zz = { 0.f, 0.f, 0.f, 0.f };
#pragma unroll
    for (int i = 0; i < 4; i++)
#pragma unroll
        for (int j = 0; j < 4; j++) acc[i][j] = zz;
    for (int kt = 0; kt < (K >> 6); ++kt) {
        __syncthreads();
#pragma unroll
        for (int i = 0; i < 4; i++) {
            int cbase = i * 256 + w * 64;
            int c = cbase + l, row = c >> 3, kc = c & 7;
            gload_lds16(A + (size_t)(m0 + row) * K + kt * 64 + kc * 8, As + (size_t)cbase * 8);
            gload_lds16(Bt + (size_t)(n0 + row) * K + kt * 64 + kc * 8, Bs + (size_t)cbase * 8);
        }
        __syncthreads();
#pragma unroll
        for (int kk = 0; kk < 2; kk++) {
            bf16x8 af[4], bfv[4];
#pragma unroll
            for (int mi = 0; mi < 4; mi++)
                af[mi] = *(const bf16x8*)(As + (wr * 64 + mi * 16 + (l & 15)) * 64 + kk * 32 + (l >> 4) * 8);
#pragma unroll
            for (int ni = 0; ni < 4; ni++)
                bfv[ni] = *(const bf16x8*)(Bs + (wc * 64 + ni * 16 + (l & 15)) * 64 + kk * 32 + (l >> 4) * 8);
#pragma unroll
            for (int mi = 0; mi < 4; mi++)
#pragma unroll
                for (int ni = 0; ni < 4; ni++)
                    acc[mi][ni] = __builtin_amdgcn_mfma_f32_16x16x32_bf16(af[mi], bfv[ni], acc[mi][ni], 0, 0, 0);
        }
    }
    const int lr = l >> 4, lc = l & 15;
#pragma unroll
    for (int ni = 0; ni < 4; ni++) {
        int col = n0 + wc * 64 + ni * 16 + lc;
        float bv = bias[col];
#pragma unroll
        for (int mi = 0; mi < 4; mi++)
#pragma unroll
            for (int r = 0; r < 4; r++) {
                int row = m0 + wr * 64 + mi * 16 + lr * 4 + r;
                C[(size_t)row * 4096 + col] = acc[mi][ni][r] + bv;
            }
    }
}

// ================= fused: LSTM (blocks 0..63) + proj workers (64..255), 512thr, 1 block/CU =====
// lstm: r11-proven protocol — distributed GROUP poll (wave w confirms its 8 source flags via
// lanes 0-7 + ballot) then 4 full-wave 1KB global_load_lds into slice-contiguous LDS.
// proj: r9-proven 8-wave 128x256 dbuf tiles, swizzled, dynamic per-chunk queue.
// THIS ROUND (single change vs r11): `out` epilogue stores are NON-TEMPORAL (nt) so the
// 262MB output stream does not evict whqt from LLC -> whqt stays LLC-resident across the
// 16 chunk sweeps -> less HBM re-fetch + less LLC contention on the lstm critical path.
__global__ __launch_bounds__(512, 2) void lstm_proj(
    u16* __restrict__ hs,          // [128*16][1024] bf16, row = t*16+b
    const float* __restrict__ xz,  // [128*16][4096] f32
    const float* __restrict__ Wi, const float* __restrict__ Wf,
    const float* __restrict__ Wo, const float* __restrict__ Wc,
    u32* __restrict__ flags,
    const u16* __restrict__ whqt,  // [32000][1024] bf16
    const float* __restrict__ bq, float* __restrict__ out) {
    __shared__ __align__(16) char smem[98816];   // >81920 -> exactly 1 block/CU
    const int bx = blockIdx.x;
    const int tid = threadIdx.x;
    const int w = tid >> 6, l = tid & 63;

    // one-time cache invalidate (cross-replay staleness in L1/L2)
    if (tid == 0)
        __hip_atomic_fetch_add(&flags[(size_t)(ACQ_BASE + (bx & 255)) * FLAG_STRIDE], 0u,
                               __ATOMIC_ACQ_REL, __HIP_MEMORY_SCOPE_AGENT);

    if (bx < 64) {
        // ---------------- LSTM path ----------------
        u16* hstage = (u16*)smem;                              // 32 KB: [jw=64][b=16][2x16B]
        float (*zlds)[16][17] = (float (*)[16][17])(void*)(smem + 32768);
        u32* lds_cnt = (u32*)(smem + 37632);
        const int j = bx;
        const int row = l & 15, hi = l >> 4;
        if (tid == 0) *lds_cnt = 0;

        bf16x8 wf[32];
        if (w < 4) {
            const float* Wg = (w == 0) ? Wi : (w == 1) ? Wf : (w == 2) ? Wo : Wc;
#pragma unroll
            for (int kk = 0; kk < 32; ++kk)
#pragma unroll
                for (int e = 0; e < 8; ++e)
                    wf[kk][e] = f2bf(Wg[(size_t)(512 + kk * 32 + hi * 8 + e) * 1024 + j * 16 + row]);
        }
        __syncthreads();

        const int b = tid >> 4, hc = tid & 15;
        float cst = 0.f;
        float cz0 = 0.f, cz1 = 0.f, cz2 = 0.f, cz3 = 0.f;
        if (tid < 256) {
            const float* xr0 = xz + (size_t)b * 4096 + j * 16 + hc;
            cz0 = xr0[0]; cz1 = xr0[1024]; cz2 = xr0[2048]; cz3 = xr0[3072];
        }

        for (int t = 0; t < 128; ++t) {
            if (t > 0) {
                const u16* hbase = hs + (size_t)(t - 1) * 16 * 1024;
                // ---- confirm ALL 8 source flags for this wave (lanes 0-7 poll in parallel)
                {
                    int spins = 0;
                    while (true) {
                        u32 f = 1u;
                        if (l < 8)
                            f = __hip_atomic_load(
                                    &flags[(size_t)((t - 1) * 64 + 8 * w + l) * FLAG_STRIDE],
                                    __ATOMIC_RELAXED, __HIP_MEMORY_SCOPE_SYSTEM);
                        if (__ballot(f != 0u) == ~0ull) break;
                        __builtin_amdgcn_s_sleep(1);
                        if (++spins > (1 << 20)) break;   // safety bail
                    }
                }
                // ---- THEN stage the 8 slices: 4 full-wave 1KB loads (2 slices each)
#pragma unroll
                for (int q = 0; q < 4; ++q) {
                    int jw0 = 8 * w + 2 * q;
                    gload_lds16(hbase + (size_t)((l & 31) >> 1) * 1024
                                      + (jw0 + (l >> 5)) * 16 + (l & 1) * 8,
                                hstage + (size_t)jw0 * 256);
                }
            }
            float nz0 = 0.f, nz1 = 0.f, nz2 = 0.f, nz3 = 0.f;
            if (t < 127 && tid < 256) {
                const float* xr = xz + (size_t)((t + 1) * 16 + b) * 4096 + j * 16 + hc;
                nz0 = xr[0]; nz1 = xr[1024]; nz2 = xr[2048]; nz3 = xr[3072];
            }
            __syncthreads();   // B2: per-wave vmcnt drain at barrier -> all 64 slices in LDS
            if (t > 0) {
                if (tid == 0)  // all flags of t-1 confirmed block-wide -> epoch
                    __hip_atomic_store(&flags[(size_t)(EPOCH_BASE + j) * FLAG_STRIDE], (u32)t,
                                       __ATOMIC_RELAXED, __HIP_MEMORY_SCOPE_SYSTEM);
                if (w < 4) {
                    f32x4 zv = { 0.f, 0.f, 0.f, 0.f };
                    f32x4 ac0 = zv, ac1 = zv, ac2 = zv, ac3 = zv;
#pragma unroll
                    for (int kk = 0; kk < 32; kk += 4) {
#pragma unroll
                        for (int u = 0; u < 4; ++u) {
                            // A-frag: h[row][ (kk+u)*32 + hi*8 .. +8 ] from slice layout
                            int base = (2 * (kk + u) + (hi >> 1)) * 256 + row * 16 + (hi & 1) * 8;
                            bf16x8 a = *(const bf16x8*)(hstage + base);
                            f32x4& ac = (u == 0) ? ac0 : (u == 1) ? ac1 : (u == 2) ? ac2 : ac3;
                            ac = __builtin_amdgcn_mfma_f32_16x16x32_bf16(a, wf[kk + u], ac, 0, 0, 0);
                        }
                    }
                    f32x4 acc = (ac0 + ac1) + (ac2 + ac3);
#pragma unroll
                    for (int r = 0; r < 4; ++r)
                        zlds[w][hi * 4 + r][row] = acc[r];
                }
            }
            __syncthreads();       // B3: zlds ready; also guards hstage reuse next step
            if (tid < 256) {
                float zi = cz0, zf = cz1, zo = cz2, zc = cz3;
                if (t > 0) {
                    zi += zlds[0][b][hc]; zf += zlds[1][b][hc];
                    zo += zlds[2][b][hc]; zc += zlds[3][b][hc];
                }
                float ig = 1.f / (1.f + __expf(-zi));
                float fg = 1.f / (1.f + __expf(-zf));
                float og = 1.f / (1.f + __expf(-zo));
                float gg = tanhf(zc);
                cst = fg * cst + ig * gg;
                float h = og * tanhf(cst);
                float hn = __shfl_xor(h, 1);
                if (!(l & 1)) {
                    unsigned pk = (unsigned)f2bf(h) | ((unsigned)f2bf(hn) << 16);
                    u32* dst = (u32*)hs + (((size_t)(t * 16 + b) * 1024 + j * 16 + hc) >> 1);
                    __hip_atomic_store(dst, pk, __ATOMIC_RELAXED, __HIP_MEMORY_SCOPE_SYSTEM);
                }
                cz0 = nz0; cz1 = nz1; cz2 = nz2; cz3 = nz3;
            }
            if (w < 4) {
                asm volatile("s_waitcnt vmcnt(0)" ::: "memory");
                if (l == 0) {
                    u32 old = atomicAdd(lds_cnt, 1u);
                    if (old == (u32)(4 * t + 3))
                        __hip_atomic_store(&flags[(size_t)(t * 64 + j) * FLAG_STRIDE], 1u,
                                           __ATOMIC_RELAXED, __HIP_MEMORY_SCOPE_SYSTEM);
                }
            }
        }
        // final: confirm step 127 globally, then epoch = 128
        if (w == 0) {
            int spins = 0;
            while (true) {
                u32 f = __hip_atomic_load(&flags[(size_t)(127 * 64 + l) * FLAG_STRIDE],
                                          __ATOMIC_RELAXED, __HIP_MEMORY_SCOPE_SYSTEM);
                if (__ballot(f != 0) == ~0ull) break;
                __builtin_amdgcn_s_sleep(1);
                if (++spins > (1 << 20)) break;
            }
            if (l == 0)
                __hip_atomic_store(&flags[(size_t)(EPOCH_BASE + j) * FLAG_STRIDE], 128u,
                                   __ATOMIC_RELAXED, __HIP_MEMORY_SCOPE_SYSTEM);
        }
        return;
    }

    // ---------------- projection worker: 8 waves, 128x256 tile, dbuf LDS, swizzled ----------------
    u16* As = (u16*)smem;                   // 2 x 16 KB
    u16* Bs = (u16*)(smem + 32768);         // 2 x 32 KB
    u32* idx_slot = (u32*)(smem + 98304);
    const int wr = w >> 2, wc = w & 3;
    const int lr = l >> 4, lc = l & 15;

    for (int m = 0; m < 16; ++m) {
        if (w == 0) {                       // wait for t-chunk m readiness (one epoch line)
            const u32 need = (u32)(8 * m + 8);
            int spins = 0;
            while (__hip_atomic_load(&flags[(size_t)(EPOCH_BASE + (bx & 63)) * FLAG_STRIDE],
                                     __ATOMIC_RELAXED, __HIP_MEMORY_SCOPE_SYSTEM) < need) {
                __builtin_amdgcn_s_sleep(8);
                if (++spins > (1 << 20)) break;
            }
        }
        __syncthreads();

        while (true) {
            if (tid == 0)
                *idx_slot = __hip_atomic_fetch_add(&flags[(size_t)(QCNT_BASE + m) * FLAG_STRIDE],
                                                   1u, __ATOMIC_RELAXED, __HIP_MEMORY_SCOPE_AGENT);
            __syncthreads();
            u32 idx = *idx_slot;
            __syncthreads();
            if (idx >= NTILE) break;
            const int n0 = (int)idx * 256;

            auto STAGE = [&](int bi, int kt) {
#pragma unroll
                for (int i = 0; i < 2; ++i) {           // A: 128 rows x 8 chunks
                    int C = i * 512 + tid, r = C >> 3, c = C & 7;
                    int sc = c ^ (r & 7);
                    int arow = (8 * m + (r & 7)) * 16 + (r >> 3);   // b-major within chunk
                    gload_lds16(hs + (size_t)arow * 1024 + kt * 64 + sc * 8,
                                As + (size_t)(bi * 8192 + (i * 512 + w * 64) * 8));
                }
#pragma unroll
                for (int i = 0; i < 4; ++i) {           // B: 256 rows x 8 chunks
                    int C = i * 512 + tid, r = C >> 3, c = C & 7;
                    int sc = c ^ (r & 7);
                    gload_lds16(whqt + (size_t)(n0 + r) * 1024 + kt * 64 + sc * 8,
                                Bs + (size_t)(bi * 16384 + (i * 512 + w * 64) * 8));
                }
            };

            f32x4 acc[4][4];
            f32x4 zz = { 0.f, 0.f, 0.f, 0.f };
#pragma unroll
            for (int i = 0; i < 4; i++)
#pragma unroll
                for (int jj = 0; jj < 4; jj++) acc[i][jj] = zz;

            int cur = 0;
            STAGE(0, 0);
            __syncthreads();
            for (int kt = 0; kt < 16; ++kt) {
                if (kt + 1 < 16) STAGE(cur ^ 1, kt + 1);
                const u16* Ab = As + cur * 8192;
                const u16* Bb = Bs + cur * 16384;
#pragma unroll
                for (int kk = 0; kk < 2; ++kk) {
                    bf16x8 af[4], bf[4];
#pragma unroll
                    for (int mi = 0; mi < 4; ++mi) {
                        int rA = wr * 64 + mi * 16 + lc;
                        int s = (kk * 4 + lr) ^ (rA & 7);
                        af[mi] = *(const bf16x8*)(Ab + rA * 64 + s * 8);
                    }
#pragma unroll
                    for (int ni = 0; ni < 4; ++ni) {
                        int rB = wc * 64 + ni * 16 + lc;
                        int s = (kk * 4 + lr) ^ (rB & 7);
                        bf[ni] = *(const bf16x8*)(Bb + rB * 64 + s * 8);
                    }
#pragma unroll
                    for (int mi = 0; mi < 4; ++mi)
#pragma unroll
                        for (int ni = 0; ni < 4; ++ni)
                            acc[mi][ni] = __builtin_amdgcn_mfma_f32_16x16x32_bf16(af[mi], bf[ni], acc[mi][ni], 0, 0, 0);
                }
                __syncthreads();   // drains vmcnt (next stage landed) + guards buf reuse
                cur ^= 1;
            }
#pragma unroll
            for (int ni = 0; ni < 4; ni++) {
                int col = n0 + wc * 64 + ni * 16 + lc;
                float bv = bq[col];
#pragma unroll
                for (int mi = 0; mi < 4; mi++) {
                    int r0 = wr * 64 + mi * 16 + lr * 4;
                    int bb = r0 >> 3;
                    int t0 = 8 * m + (r0 & 7);
                    f32x4 st = { acc[mi][ni][0] + bv, acc[mi][ni][1] + bv,
                                 acc[mi][ni][2] + bv, acc[mi][ni][3] + bv };
                    float* dst = out + (size_t)bb * 4096000 + (size_t)col * 128 + t0;
                    // non-temporal: don't let the 262MB output stream evict whqt from LLC
                    asm volatile("global_store_dwordx4 %0, %1, off nt"
                                 :: "v"(dst), "v"(st) : "memory");
                }
            }
        }
    }
}

extern "C" void kernel_launch(void* const* d_in, const int* in_sizes, int n_in,
                              void* d_out, int out_size, void* d_ws, size_t ws_size,
                              hipStream_t stream) {
    const int*   sent = (const int*)d_in[0];
    const float* emb  = (const float*)d_in[1];
    const float* W_i  = (const float*)d_in[2];
    const float* b_i  = (const float*)d_in[3];
    const float* W_f  = (const float*)d_in[4];
    const float* b_f  = (const float*)d_in[5];
    const float* W_o  = (const float*)d_in[6];
    const float* b_o  = (const float*)d_in[7];
    const float* W_c  = (const float*)d_in[8];
    const float* b_c  = (const float*)d_in[9];
    const float* W_hq = (const float*)d_in[10];
    const float* b_q  = (const float*)d_in[11];
    float* out = (float*)d_out;

    char* ws = (char*)d_ws;
    size_t off = 0;
    auto alloc = [&](size_t bytes) { void* p = ws + off; off += (bytes + 255) & ~255ull; return p; };
    u32*   flags = (u32*)alloc((size_t)FLAG_WORDS * 4);
    float* b4   = (float*)alloc((size_t)4096 * 4);
    u16*   xb   = (u16*)alloc((size_t)2048 * 512 * 2);
    u16*   wxt  = (u16*)alloc((size_t)4096 * 512 * 2);
    u16*   hs   = (u16*)alloc((size_t)2048 * 1024 * 2);
    float* xz   = (float*)alloc((size_t)2048 * 4096 * 4);
    u16*   whqt = (u16*)alloc((size_t)32000 * 1024 * 2);

    hipMemsetAsync(flags, 0, (size_t)FLAG_WORDS * 4, stream);
    prep<<<35088, 256, 0, stream>>>(sent, emb, xb, b_i, b_f, b_o, b_c, b4,
                                    W_i, W_f, W_o, W_c, wxt, W_hq, whqt);
    gemm_xz<<<dim3(16, 32), 256, 0, stream>>>(xb, wxt, b4, xz);
    // fused: 64 lstm blocks + 192 proj workers, 512 threads, 1 block/CU
    lstm_proj<<<256, 512, 0, stream>>>(hs, xz, W_i, W_f, W_o, W_c,
                                       flags, whqt, b_q, out);
}

// Round 15
// 662.386 us; speedup vs baseline: 1.1108x; 1.1108x over previous
//
#include <hip/hip_runtime.h>
#include <math.h>

typedef float f32x4 __attribute__((ext_vector_type(4)));
typedef short bf16x8 __attribute__((ext_vector_type(8)));
typedef unsigned short u16;
typedef unsigned int u32;

#define FLAG_STRIDE 16            // one u32 flag per 64B line
#define ACQ_BASE    8192          // 256 acquire-dummy lines (after 128*64 step flags)
#define EPOCH_BASE  8448          // 64 epoch lines
#define QCNT_BASE   8512          // n-tile queue (single line)
#define FLAG_WORDS  ((QCNT_BASE + 16) * FLAG_STRIDE)
#define NTILE       125           // 32000 / 256 proj n-tiles

__device__ __forceinline__ u16 f2bf(float f) {
    union { float f; unsigned u; } x; x.f = f;
    unsigned r = x.u + 0x7fff + ((x.u >> 16) & 1);   // RNE
    return (u16)(r >> 16);
}

// async global->LDS, 16B/lane. LDS dest wave-uniform base; HW adds lane*16. Global src per-lane.
__device__ __forceinline__ void gload_lds16(const u16* g, u16* l) {
    __builtin_amdgcn_global_load_lds(
        (const __attribute__((address_space(1))) void*)g,
        (__attribute__((address_space(3))) void*)l, 16, 0, 0);
}

// ================= prep: gather + bias concat + all transposes in ONE launch =================
__global__ __launch_bounds__(256) void prep(
    const int* __restrict__ sent, const float* __restrict__ emb, u16* __restrict__ xb,
    const float* __restrict__ bi, const float* __restrict__ bf_,
    const float* __restrict__ bo, const float* __restrict__ bc, float* __restrict__ b4,
    const float* __restrict__ Wi, const float* __restrict__ Wf,
    const float* __restrict__ Wo, const float* __restrict__ Wc, u16* __restrict__ wxt,
    const float* __restrict__ Whq, u16* __restrict__ whqt) {
    __shared__ float tile[32][33];
    const int bx = blockIdx.x, tid = threadIdx.x;
    if (bx < 1024) {                       // embedding gather, 2 rows/WG
        int row = bx * 2 + (tid >> 7);     // t*16+b
        int t = row >> 4, b = row & 15;
        int idx = sent[b * 128 + t];
        float4 v = ((const float4*)(emb + (size_t)idx * 512))[tid & 127];
        ushort4 s = { f2bf(v.x), f2bf(v.y), f2bf(v.z), f2bf(v.w) };
        ((ushort4*)(xb + (size_t)row * 512))[tid & 127] = s;
        return;
    }
    if (bx < 1040) {                       // b4
        int i = (bx - 1024) * 256 + tid;
        const float* p = (i < 1024) ? bi : (i < 2048) ? bf_ : (i < 3072) ? bo : bc;
        b4[i] = p[i & 1023];
        return;
    }
    const float* in; u16* out; int ldin, ldout, rt, ct;
    if (bx < 3088) {                       // 4x Wx: rows 0..512 of W_g[1536][1024]
        int q = bx - 1040, g = q >> 9, r = q & 511;
        in = (g == 0) ? Wi : (g == 1) ? Wf : (g == 2) ? Wo : Wc;
        ldin = 1024; out = wxt + (size_t)g * 1024 * 512; ldout = 512;
        rt = (r >> 5) * 32; ct = (r & 31) * 32;
    } else {                               // W_hq [1024][32000] -> whqt [32000][1024]
        int q = bx - 3088;
        in = Whq; ldin = 32000; out = whqt; ldout = 1024;
        rt = (q / 1000) * 32; ct = (q % 1000) * 32;
    }
    {
        int r = tid >> 3, cq = (tid & 7) * 4;
        float4 v = *(const float4*)(in + (size_t)(rt + r) * ldin + ct + cq);
        tile[r][cq] = v.x; tile[r][cq + 1] = v.y; tile[r][cq + 2] = v.z; tile[r][cq + 3] = v.w;
        __syncthreads();
        int c = tid >> 3, rq = (tid & 7) * 4;
        ushort4 s = { f2bf(tile[rq][c]), f2bf(tile[rq + 1][c]),
                      f2bf(tile[rq + 2][c]), f2bf(tile[rq + 3][c]) };
        *(ushort4*)(out + (size_t)(ct + c) * ldout + rt + rq) = s;
    }
}

// ================= xz GEMM: xz[M][4096] = xb[M][512](bf16) @ wxt[4096][512]^T + b4 =================
__global__ __launch_bounds__(256) void gemm_xz(
    const u16* __restrict__ A, const u16* __restrict__ Bt,
    const float* __restrict__ bias, float* __restrict__ C) {
    const int tid = threadIdx.x;
    const int l = tid & 63, w = tid >> 6;
    const int wr = w >> 1, wc = w & 1;
    const int m0 = blockIdx.x * 128, n0 = blockIdx.y * 128;
    const int K = 512;
    __shared__ __align__(16) u16 As[128 * 64];
    __shared__ __align__(16) u16 Bs[128 * 64];
    f32x4 acc[4][4];
    f32x4 zz = { 0.f, 0.f, 0.f, 0.f };
#pragma unroll
    for (int i = 0; i < 4; i++)
#pragma unroll
        for (int j = 0; j < 4; j++) acc[i][j] = zz;
    for (int kt = 0; kt < (K >> 6); ++kt) {
        __syncthreads();
#pragma unroll
        for (int i = 0; i < 4; i++) {
            int cbase = i * 256 + w * 64;
            int c = cbase + l, row = c >> 3, kc = c & 7;
            gload_lds16(A + (size_t)(m0 + row) * K + kt * 64 + kc * 8, As + (size_t)cbase * 8);
            gload_lds16(Bt + (size_t)(n0 + row) * K + kt * 64 + kc * 8, Bs + (size_t)cbase * 8);
        }
        __syncthreads();
#pragma unroll
        for (int kk = 0; kk < 2; kk++) {
            bf16x8 af[4], bfv[4];
#pragma unroll
            for (int mi = 0; mi < 4; mi++)
                af[mi] = *(const bf16x8*)(As + (wr * 64 + mi * 16 + (l & 15)) * 64 + kk * 32 + (l >> 4) * 8);
#pragma unroll
            for (int ni = 0; ni < 4; ni++)
                bfv[ni] = *(const bf16x8*)(Bs + (wc * 64 + ni * 16 + (l & 15)) * 64 + kk * 32 + (l >> 4) * 8);
#pragma unroll
            for (int mi = 0; mi < 4; mi++)
#pragma unroll
                for (int ni = 0; ni < 4; ni++)
                    acc[mi][ni] = __builtin_amdgcn_mfma_f32_16x16x32_bf16(af[mi], bfv[ni], acc[mi][ni], 0, 0, 0);
        }
    }
    const int lr = l >> 4, lc = l & 15;
#pragma unroll
    for (int ni = 0; ni < 4; ni++) {
        int col = n0 + wc * 64 + ni * 16 + lc;
        float bv = bias[col];
#pragma unroll
        for (int mi = 0; mi < 4; mi++)
#pragma unroll
            for (int r = 0; r < 4; r++) {
                int row = m0 + wr * 64 + mi * 16 + lr * 4 + r;
                C[(size_t)row * 4096 + col] = acc[mi][ni][r] + bv;
            }
    }
}

// ================= fused: LSTM (blocks 0..63) + proj workers (64..255), 512thr, 1 block/CU =====
// lstm: r11-proven protocol — distributed GROUP poll (wave w confirms its 8 source flags via
// lanes 0-7 + ballot) then 4 full-wave 1KB global_load_lds into slice-contiguous LDS.
// proj (THIS ROUND, n-outer): each worker grabs ONE n-tile (256 cols) for the whole run and
// sweeps m=0..15 over it -> its 512KB whqt slice is HBM-fetched once and L2/LLC-served for
// the other 15 chunks (was: all 125 tiles re-streamed every chunk -> 9x whqt HBM re-fetch).
__global__ __launch_bounds__(512, 2) void lstm_proj(
    u16* __restrict__ hs,          // [128*16][1024] bf16, row = t*16+b
    const float* __restrict__ xz,  // [128*16][4096] f32
    const float* __restrict__ Wi, const float* __restrict__ Wf,
    const float* __restrict__ Wo, const float* __restrict__ Wc,
    u32* __restrict__ flags,
    const u16* __restrict__ whqt,  // [32000][1024] bf16
    const float* __restrict__ bq, float* __restrict__ out) {
    __shared__ __align__(16) char smem[98816];   // >81920 -> exactly 1 block/CU
    const int bx = blockIdx.x;
    const int tid = threadIdx.x;
    const int w = tid >> 6, l = tid & 63;

    // one-time cache invalidate (cross-replay staleness in L1/L2)
    if (tid == 0)
        __hip_atomic_fetch_add(&flags[(size_t)(ACQ_BASE + (bx & 255)) * FLAG_STRIDE], 0u,
                               __ATOMIC_ACQ_REL, __HIP_MEMORY_SCOPE_AGENT);

    if (bx < 64) {
        // ---------------- LSTM path ----------------
        u16* hstage = (u16*)smem;                              // 32 KB: [jw=64][b=16][2x16B]
        float (*zlds)[16][17] = (float (*)[16][17])(void*)(smem + 32768);
        u32* lds_cnt = (u32*)(smem + 37632);
        const int j = bx;
        const int row = l & 15, hi = l >> 4;
        if (tid == 0) *lds_cnt = 0;

        bf16x8 wf[32];
        if (w < 4) {
            const float* Wg = (w == 0) ? Wi : (w == 1) ? Wf : (w == 2) ? Wo : Wc;
#pragma unroll
            for (int kk = 0; kk < 32; ++kk)
#pragma unroll
                for (int e = 0; e < 8; ++e)
                    wf[kk][e] = f2bf(Wg[(size_t)(512 + kk * 32 + hi * 8 + e) * 1024 + j * 16 + row]);
        }
        __syncthreads();

        const int b = tid >> 4, hc = tid & 15;
        float cst = 0.f;
        float cz0 = 0.f, cz1 = 0.f, cz2 = 0.f, cz3 = 0.f;
        if (tid < 256) {
            const float* xr0 = xz + (size_t)b * 4096 + j * 16 + hc;
            cz0 = xr0[0]; cz1 = xr0[1024]; cz2 = xr0[2048]; cz3 = xr0[3072];
        }

        for (int t = 0; t < 128; ++t) {
            if (t > 0) {
                const u16* hbase = hs + (size_t)(t - 1) * 16 * 1024;
                // ---- confirm ALL 8 source flags for this wave (lanes 0-7 poll in parallel)
                {
                    int spins = 0;
                    while (true) {
                        u32 f = 1u;
                        if (l < 8)
                            f = __hip_atomic_load(
                                    &flags[(size_t)((t - 1) * 64 + 8 * w + l) * FLAG_STRIDE],
                                    __ATOMIC_RELAXED, __HIP_MEMORY_SCOPE_SYSTEM);
                        if (__ballot(f != 0u) == ~0ull) break;
                        __builtin_amdgcn_s_sleep(1);
                        if (++spins > (1 << 20)) break;   // safety bail
                    }
                }
                // ---- THEN stage the 8 slices: 4 full-wave 1KB loads (2 slices each)
#pragma unroll
                for (int q = 0; q < 4; ++q) {
                    int jw0 = 8 * w + 2 * q;
                    gload_lds16(hbase + (size_t)((l & 31) >> 1) * 1024
                                      + (jw0 + (l >> 5)) * 16 + (l & 1) * 8,
                                hstage + (size_t)jw0 * 256);
                }
            }
            float nz0 = 0.f, nz1 = 0.f, nz2 = 0.f, nz3 = 0.f;
            if (t < 127 && tid < 256) {
                const float* xr = xz + (size_t)((t + 1) * 16 + b) * 4096 + j * 16 + hc;
                nz0 = xr[0]; nz1 = xr[1024]; nz2 = xr[2048]; nz3 = xr[3072];
            }
            __syncthreads();   // B2: per-wave vmcnt drain at barrier -> all 64 slices in LDS
            if (t > 0) {
                if (tid == 0)  // all flags of t-1 confirmed block-wide -> epoch
                    __hip_atomic_store(&flags[(size_t)(EPOCH_BASE + j) * FLAG_STRIDE], (u32)t,
                                       __ATOMIC_RELAXED, __HIP_MEMORY_SCOPE_SYSTEM);
                if (w < 4) {
                    f32x4 zv = { 0.f, 0.f, 0.f, 0.f };
                    f32x4 ac0 = zv, ac1 = zv, ac2 = zv, ac3 = zv;
#pragma unroll
                    for (int kk = 0; kk < 32; kk += 4) {
#pragma unroll
                        for (int u = 0; u < 4; ++u) {
                            // A-frag: h[row][ (kk+u)*32 + hi*8 .. +8 ] from slice layout
                            int base = (2 * (kk + u) + (hi >> 1)) * 256 + row * 16 + (hi & 1) * 8;
                            bf16x8 a = *(const bf16x8*)(hstage + base);
                            f32x4& ac = (u == 0) ? ac0 : (u == 1) ? ac1 : (u == 2) ? ac2 : ac3;
                            ac = __builtin_amdgcn_mfma_f32_16x16x32_bf16(a, wf[kk + u], ac, 0, 0, 0);
                        }
                    }
                    f32x4 acc = (ac0 + ac1) + (ac2 + ac3);
#pragma unroll
                    for (int r = 0; r < 4; ++r)
                        zlds[w][hi * 4 + r][row] = acc[r];
                }
            }
            __syncthreads();       // B3: zlds ready; also guards hstage reuse next step
            if (tid < 256) {
                float zi = cz0, zf = cz1, zo = cz2, zc = cz3;
                if (t > 0) {
                    zi += zlds[0][b][hc]; zf += zlds[1][b][hc];
                    zo += zlds[2][b][hc]; zc += zlds[3][b][hc];
                }
                float ig = 1.f / (1.f + __expf(-zi));
                float fg = 1.f / (1.f + __expf(-zf));
                float og = 1.f / (1.f + __expf(-zo));
                float gg = tanhf(zc);
                cst = fg * cst + ig * gg;
                float h = og * tanhf(cst);
                float hn = __shfl_xor(h, 1);
                if (!(l & 1)) {
                    unsigned pk = (unsigned)f2bf(h) | ((unsigned)f2bf(hn) << 16);
                    u32* dst = (u32*)hs + (((size_t)(t * 16 + b) * 1024 + j * 16 + hc) >> 1);
                    __hip_atomic_store(dst, pk, __ATOMIC_RELAXED, __HIP_MEMORY_SCOPE_SYSTEM);
                }
                cz0 = nz0; cz1 = nz1; cz2 = nz2; cz3 = nz3;
            }
            if (w < 4) {
                asm volatile("s_waitcnt vmcnt(0)" ::: "memory");
                if (l == 0) {
                    u32 old = atomicAdd(lds_cnt, 1u);
                    if (old == (u32)(4 * t + 3))
                        __hip_atomic_store(&flags[(size_t)(t * 64 + j) * FLAG_STRIDE], 1u,
                                           __ATOMIC_RELAXED, __HIP_MEMORY_SCOPE_SYSTEM);
                }
            }
        }
        // final: confirm step 127 globally, then epoch = 128
        if (w == 0) {
            int spins = 0;
            while (true) {
                u32 f = __hip_atomic_load(&flags[(size_t)(127 * 64 + l) * FLAG_STRIDE],
                                          __ATOMIC_RELAXED, __HIP_MEMORY_SCOPE_SYSTEM);
                if (__ballot(f != 0) == ~0ull) break;
                __builtin_amdgcn_s_sleep(1);
                if (++spins > (1 << 20)) break;
            }
            if (l == 0)
                __hip_atomic_store(&flags[(size_t)(EPOCH_BASE + j) * FLAG_STRIDE], 128u,
                                   __ATOMIC_RELAXED, __HIP_MEMORY_SCOPE_SYSTEM);
        }
        return;
    }

    // ---------------- projection worker: ONE n-tile, m-sweep over 16 chunks ----------------
    u16* As = (u16*)smem;                   // 2 x 16 KB
    u16* Bs = (u16*)(smem + 32768);         // 2 x 32 KB
    u32* idx_slot = (u32*)(smem + 98304);
    const int wr = w >> 2, wc = w & 3;
    const int lr = l >> 4, lc = l & 15;

    if (tid == 0)
        *idx_slot = __hip_atomic_fetch_add(&flags[(size_t)QCNT_BASE * FLAG_STRIDE],
                                           1u, __ATOMIC_RELAXED, __HIP_MEMORY_SCOPE_AGENT);
    __syncthreads();
    const u32 myIdx = *idx_slot;
    if (myIdx >= NTILE) return;             // 67 surplus workers exit
    const int n0 = (int)myIdx * 256;

    for (int m = 0; m < 16; ++m) {
        if (w == 0) {                       // wait for t-chunk m readiness (one epoch line)
            const u32 need = (u32)(8 * m + 8);
            int spins = 0;
            while (__hip_atomic_load(&flags[(size_t)(EPOCH_BASE + (bx & 63)) * FLAG_STRIDE],
                                     __ATOMIC_RELAXED, __HIP_MEMORY_SCOPE_SYSTEM) < need) {
                __builtin_amdgcn_s_sleep(8);
                if (++spins > (1 << 20)) break;
            }
        }
        __syncthreads();

        auto STAGE = [&](int bi, int kt) {
#pragma unroll
            for (int i = 0; i < 2; ++i) {           // A: 128 rows x 8 chunks
                int C = i * 512 + tid, r = C >> 3, c = C & 7;
                int sc = c ^ (r & 7);
                int arow = (8 * m + (r & 7)) * 16 + (r >> 3);   // b-major within chunk
                gload_lds16(hs + (size_t)arow * 1024 + kt * 64 + sc * 8,
                            As + (size_t)(bi * 8192 + (i * 512 + w * 64) * 8));
            }
#pragma unroll
            for (int i = 0; i < 4; ++i) {           // B: 256 rows x 8 chunks
                int C = i * 512 + tid, r = C >> 3, c = C & 7;
                int sc = c ^ (r & 7);
                gload_lds16(whqt + (size_t)(n0 + r) * 1024 + kt * 64 + sc * 8,
                            Bs + (size_t)(bi * 16384 + (i * 512 + w * 64) * 8));
            }
        };

        f32x4 acc[4][4];
        f32x4 zz = { 0.f, 0.f, 0.f, 0.f };
#pragma unroll
        for (int i = 0; i < 4; i++)
#pragma unroll
            for (int jj = 0; jj < 4; jj++) acc[i][jj] = zz;

        int cur = 0;
        STAGE(0, 0);
        __syncthreads();
        for (int kt = 0; kt < 16; ++kt) {
            if (kt + 1 < 16) STAGE(cur ^ 1, kt + 1);
            const u16* Ab = As + cur * 8192;
            const u16* Bb = Bs + cur * 16384;
#pragma unroll
            for (int kk = 0; kk < 2; ++kk) {
                bf16x8 af[4], bf[4];
#pragma unroll
                for (int mi = 0; mi < 4; ++mi) {
                    int rA = wr * 64 + mi * 16 + lc;
                    int s = (kk * 4 + lr) ^ (rA & 7);
                    af[mi] = *(const bf16x8*)(Ab + rA * 64 + s * 8);
                }
#pragma unroll
                for (int ni = 0; ni < 4; ++ni) {
                    int rB = wc * 64 + ni * 16 + lc;
                    int s = (kk * 4 + lr) ^ (rB & 7);
                    bf[ni] = *(const bf16x8*)(Bb + rB * 64 + s * 8);
                }
#pragma unroll
                for (int mi = 0; mi < 4; ++mi)
#pragma unroll
                    for (int ni = 0; ni < 4; ++ni)
                        acc[mi][ni] = __builtin_amdgcn_mfma_f32_16x16x32_bf16(af[mi], bf[ni], acc[mi][ni], 0, 0, 0);
            }
            __syncthreads();   // drains vmcnt (next stage landed) + guards buf reuse
            cur ^= 1;
        }
#pragma unroll
        for (int ni = 0; ni < 4; ni++) {
            int col = n0 + wc * 64 + ni * 16 + lc;
            float bv = bq[col];
#pragma unroll
            for (int mi = 0; mi < 4; mi++) {
                int r0 = wr * 64 + mi * 16 + lr * 4;
                int bb = r0 >> 3;
                int t0 = 8 * m + (r0 & 7);
                float4 st = { acc[mi][ni][0] + bv, acc[mi][ni][1] + bv,
                              acc[mi][ni][2] + bv, acc[mi][ni][3] + bv };
                *(float4*)(out + (size_t)bb * 4096000 + (size_t)col * 128 + t0) = st;
            }
        }
    }
}

extern "C" void kernel_launch(void* const* d_in, const int* in_sizes, int n_in,
                              void* d_out, int out_size, void* d_ws, size_t ws_size,
                              hipStream_t stream) {
    const int*   sent = (const int*)d_in[0];
    const float* emb  = (const float*)d_in[1];
    const float* W_i  = (const float*)d_in[2];
    const float* b_i  = (const float*)d_in[3];
    const float* W_f  = (const float*)d_in[4];
    const float* b_f  = (const float*)d_in[5];
    const float* W_o  = (const float*)d_in[6];
    const float* b_o  = (const float*)d_in[7];
    const float* W_c  = (const float*)d_in[8];
    const float* b_c  = (const float*)d_in[9];
    const float* W_hq = (const float*)d_in[10];
    const float* b_q  = (const float*)d_in[11];
    float* out = (float*)d_out;

    char* ws = (char*)d_ws;
    size_t off = 0;
    auto alloc = [&](size_t bytes) { void* p = ws + off; off += (bytes + 255) & ~255ull; return p; };
    u32*   flags = (u32*)alloc((size_t)FLAG_WORDS * 4);
    float* b4   = (float*)alloc((size_t)4096 * 4);
    u16*   xb   = (u16*)alloc((size_t)2048 * 512 * 2);
    u16*   wxt  = (u16*)alloc((size_t)4096 * 512 * 2);
    u16*   hs   = (u16*)alloc((size_t)2048 * 1024 * 2);
    float* xz   = (float*)alloc((size_t)2048 * 4096 * 4);
    u16*   whqt = (u16*)alloc((size_t)32000 * 1024 * 2);

    hipMemsetAsync(flags, 0, (size_t)FLAG_WORDS * 4, stream);
    prep<<<35088, 256, 0, stream>>>(sent, emb, xb, b_i, b_f, b_o, b_c, b4,
                                    W_i, W_f, W_o, W_c, wxt, W_hq, whqt);
    gemm_xz<<<dim3(16, 32), 256, 0, stream>>>(xb, wxt, b4, xz);
    // fused: 64 lstm blocks + 192 proj workers (n-outer schedule), 512 threads, 1 block/CU
    lstm_proj<<<256, 512, 0, stream>>>(hs, xz, W_i, W_f, W_o, W_c,
                                       flags, whqt, b_q, out);
}

// Round 16
// 657.026 us; speedup vs baseline: 1.1199x; 1.0082x over previous
//
#include <hip/hip_runtime.h>
#include <math.h>

typedef float f32x4 __attribute__((ext_vector_type(4)));
typedef short bf16x8 __attribute__((ext_vector_type(8)));
typedef unsigned short u16;
typedef unsigned int u32;
typedef unsigned long long u64;

#define FLAG_STRIDE 16            // one u32 flag per 64B line
#define ACQ_BASE    8192          // 256 acquire-dummy lines (after 128*64 step flags)
#define EPOCH_BASE  8448          // 64 epoch lines
#define QCNT_BASE   8512          // n-tile queue (single line)
#define TCNT_BASE   8528          // whqt-transpose completion counter
#define FLAG_WORDS  ((TCNT_BASE + 1) * FLAG_STRIDE)
#define NTILE       125           // 32000 / 256 proj n-tiles

__device__ __forceinline__ u16 f2bf(float f) {
    union { float f; unsigned u; } x; x.f = f;
    unsigned r = x.u + 0x7fff + ((x.u >> 16) & 1);   // RNE
    return (u16)(r >> 16);
}

// async global->LDS, 16B/lane. LDS dest wave-uniform base; HW adds lane*16. Global src per-lane.
__device__ __forceinline__ void gload_lds16(const u16* g, u16* l) {
    __builtin_amdgcn_global_load_lds(
        (const __attribute__((address_space(1))) void*)g,
        (__attribute__((address_space(3))) void*)l, 16, 0, 0);
}

// ================= prep: gather + bias concat + Wx transposes (whqt moved into fused) ==========
__global__ __launch_bounds__(256) void prep(
    const int* __restrict__ sent, const float* __restrict__ emb, u16* __restrict__ xb,
    const float* __restrict__ bi, const float* __restrict__ bf_,
    const float* __restrict__ bo, const float* __restrict__ bc, float* __restrict__ b4,
    const float* __restrict__ Wi, const float* __restrict__ Wf,
    const float* __restrict__ Wo, const float* __restrict__ Wc, u16* __restrict__ wxt) {
    __shared__ float tile[32][33];
    const int bx = blockIdx.x, tid = threadIdx.x;
    if (bx < 1024) {                       // embedding gather, 2 rows/WG
        int row = bx * 2 + (tid >> 7);     // t*16+b
        int t = row >> 4, b = row & 15;
        int idx = sent[b * 128 + t];
        float4 v = ((const float4*)(emb + (size_t)idx * 512))[tid & 127];
        ushort4 s = { f2bf(v.x), f2bf(v.y), f2bf(v.z), f2bf(v.w) };
        ((ushort4*)(xb + (size_t)row * 512))[tid & 127] = s;
        return;
    }
    if (bx < 1040) {                       // b4
        int i = (bx - 1024) * 256 + tid;
        const float* p = (i < 1024) ? bi : (i < 2048) ? bf_ : (i < 3072) ? bo : bc;
        b4[i] = p[i & 1023];
        return;
    }
    // 4x Wx transposes: rows 0..512 of W_g[1536][1024] -> wxt[g*1024 + c][e]
    int q = bx - 1040, g = q >> 9, r = q & 511;
    const float* in = (g == 0) ? Wi : (g == 1) ? Wf : (g == 2) ? Wo : Wc;
    u16* out = wxt + (size_t)g * 1024 * 512;
    int rt = (r >> 5) * 32, ct = (r & 31) * 32;
    {
        int rr = tid >> 3, cq = (tid & 7) * 4;
        float4 v = *(const float4*)(in + (size_t)(rt + rr) * 1024 + ct + cq);
        tile[rr][cq] = v.x; tile[rr][cq + 1] = v.y; tile[rr][cq + 2] = v.z; tile[rr][cq + 3] = v.w;
        __syncthreads();
        int c = tid >> 3, rq = (tid & 7) * 4;
        ushort4 s = { f2bf(tile[rq][c]), f2bf(tile[rq + 1][c]),
                      f2bf(tile[rq + 2][c]), f2bf(tile[rq + 3][c]) };
        *(ushort4*)(out + (size_t)(ct + c) * 512 + rt + rq) = s;
    }
}

// ================= xz GEMM: xz[M][4096] = xb[M][512](bf16) @ wxt[4096][512]^T + b4 =================
__global__ __launch_bounds__(256) void gemm_xz(
    const u16* __restrict__ A, const u16* __restrict__ Bt,
    const float* __restrict__ bias, float* __restrict__ C) {
    const int tid = threadIdx.x;
    const int l = tid & 63, w = tid >> 6;
    const int wr = w >> 1, wc = w & 1;
    const int m0 = blockIdx.x * 128, n0 = blockIdx.y * 128;
    const int K = 512;
    __shared__ __align__(16) u16 As[128 * 64];
    __shared__ __align__(16) u16 Bs[128 * 64];
    f32x4 acc[4][4];
    f32x4 zz = { 0.f, 0.f, 0.f, 0.f };
#pragma unroll
    for (int i = 0; i < 4; i++)
#pragma unroll
        for (int j = 0; j < 4; j++) acc[i][j] = zz;
    for (int kt = 0; kt < (K >> 6); ++kt) {
        __syncthreads();
#pragma unroll
        for (int i = 0; i < 4; i++) {
            int cbase = i * 256 + w * 64;
            int c = cbase + l, row = c >> 3, kc = c & 7;
            gload_lds16(A + (size_t)(m0 + row) * K + kt * 64 + kc * 8, As + (size_t)cbase * 8);
            gload_lds16(Bt + (size_t)(n0 + row) * K + kt * 64 + kc * 8, Bs + (size_t)cbase * 8);
        }
        __syncthreads();
#pragma unroll
        for (int kk = 0; kk < 2; kk++) {
            bf16x8 af[4], bfv[4];
#pragma unroll
            for (int mi = 0; mi < 4; mi++)
                af[mi] = *(const bf16x8*)(As + (wr * 64 + mi * 16 + (l & 15)) * 64 + kk * 32 + (l >> 4) * 8);
#pragma unroll
            for (int ni = 0; ni < 4; ni++)
                bfv[ni] = *(const bf16x8*)(Bs + (wc * 64 + ni * 16 + (l & 15)) * 64 + kk * 32 + (l >> 4) * 8);
#pragma unroll
            for (int mi = 0; mi < 4; mi++)
#pragma unroll
                for (int ni = 0; ni < 4; ni++)
                    acc[mi][ni] = __builtin_amdgcn_mfma_f32_16x16x32_bf16(af[mi], bfv[ni], acc[mi][ni], 0, 0, 0);
        }
    }
    const int lr = l >> 4, lc = l & 15;
#pragma unroll
    for (int ni = 0; ni < 4; ni++) {
        int col = n0 + wc * 64 + ni * 16 + lc;
        float bv = bias[col];
#pragma unroll
        for (int mi = 0; mi < 4; mi++)
#pragma unroll
            for (int r = 0; r < 4; r++) {
                int row = m0 + wr * 64 + mi * 16 + lr * 4 + r;
                C[(size_t)row * 4096 + col] = acc[mi][ni][r] + bv;
            }
    }
}

// ================= fused: LSTM (blocks 0..63) + proj workers (64..255), 512thr, 1 block/CU =====
// lstm: r11-proven protocol (distributed GROUP poll + full-wave slice staging) — unchanged.
// proj: (1) cooperative whqt transpose in prologue (n-outer slack absorbs it: workers run
//       ahead of the 37us/chunk epoch cadence from chunk ~3 on), TCNT-gated;
//       (2) ONE n-tile per worker, m-sweep 0..15 (r15 champion schedule).
__global__ __launch_bounds__(512, 2) void lstm_proj(
    u16* __restrict__ hs,          // [128*16][1024] bf16, row = t*16+b
    const float* __restrict__ xz,  // [128*16][4096] f32
    const float* __restrict__ Wi, const float* __restrict__ Wf,
    const float* __restrict__ Wo, const float* __restrict__ Wc,
    u32* __restrict__ flags,
    const float* __restrict__ Whq, // [1024][32000] f32 (source)
    u16* __restrict__ whqt,        // [32000][1024] bf16 (transposed here)
    const float* __restrict__ bq, float* __restrict__ out) {
    __shared__ __align__(16) char smem[98816];   // >81920 -> exactly 1 block/CU
    const int bx = blockIdx.x;
    const int tid = threadIdx.x;
    const int w = tid >> 6, l = tid & 63;

    // one-time cache invalidate (cross-replay staleness in L1/L2)
    if (tid == 0)
        __hip_atomic_fetch_add(&flags[(size_t)(ACQ_BASE + (bx & 255)) * FLAG_STRIDE], 0u,
                               __ATOMIC_ACQ_REL, __HIP_MEMORY_SCOPE_AGENT);

    if (bx < 64) {
        // ---------------- LSTM path (r11-champion, unchanged) ----------------
        u16* hstage = (u16*)smem;                              // 32 KB: [jw=64][b=16][2x16B]
        float (*zlds)[16][17] = (float (*)[16][17])(void*)(smem + 32768);
        u32* lds_cnt = (u32*)(smem + 37632);
        const int j = bx;
        const int row = l & 15, hi = l >> 4;
        if (tid == 0) *lds_cnt = 0;

        bf16x8 wf[32];
        if (w < 4) {
            const float* Wg = (w == 0) ? Wi : (w == 1) ? Wf : (w == 2) ? Wo : Wc;
#pragma unroll
            for (int kk = 0; kk < 32; ++kk)
#pragma unroll
                for (int e = 0; e < 8; ++e)
                    wf[kk][e] = f2bf(Wg[(size_t)(512 + kk * 32 + hi * 8 + e) * 1024 + j * 16 + row]);
        }
        __syncthreads();

        const int b = tid >> 4, hc = tid & 15;
        float cst = 0.f;
        float cz0 = 0.f, cz1 = 0.f, cz2 = 0.f, cz3 = 0.f;
        if (tid < 256) {
            const float* xr0 = xz + (size_t)b * 4096 + j * 16 + hc;
            cz0 = xr0[0]; cz1 = xr0[1024]; cz2 = xr0[2048]; cz3 = xr0[3072];
        }

        for (int t = 0; t < 128; ++t) {
            if (t > 0) {
                const u16* hbase = hs + (size_t)(t - 1) * 16 * 1024;
                // ---- confirm ALL 8 source flags for this wave (lanes 0-7 poll in parallel)
                {
                    int spins = 0;
                    while (true) {
                        u32 f = 1u;
                        if (l < 8)
                            f = __hip_atomic_load(
                                    &flags[(size_t)((t - 1) * 64 + 8 * w + l) * FLAG_STRIDE],
                                    __ATOMIC_RELAXED, __HIP_MEMORY_SCOPE_SYSTEM);
                        if (__ballot(f != 0u) == ~0ull) break;
                        __builtin_amdgcn_s_sleep(1);
                        if (++spins > (1 << 20)) break;   // safety bail
                    }
                }
                // ---- THEN stage the 8 slices: 4 full-wave 1KB loads (2 slices each)
#pragma unroll
                for (int q = 0; q < 4; ++q) {
                    int jw0 = 8 * w + 2 * q;
                    gload_lds16(hbase + (size_t)((l & 31) >> 1) * 1024
                                      + (jw0 + (l >> 5)) * 16 + (l & 1) * 8,
                                hstage + (size_t)jw0 * 256);
                }
            }
            float nz0 = 0.f, nz1 = 0.f, nz2 = 0.f, nz3 = 0.f;
            if (t < 127 && tid < 256) {
                const float* xr = xz + (size_t)((t + 1) * 16 + b) * 4096 + j * 16 + hc;
                nz0 = xr[0]; nz1 = xr[1024]; nz2 = xr[2048]; nz3 = xr[3072];
            }
            __syncthreads();   // B2: per-wave vmcnt drain at barrier -> all 64 slices in LDS
            if (t > 0) {
                if (tid == 0)  // all flags of t-1 confirmed block-wide -> epoch
                    __hip_atomic_store(&flags[(size_t)(EPOCH_BASE + j) * FLAG_STRIDE], (u32)t,
                                       __ATOMIC_RELAXED, __HIP_MEMORY_SCOPE_SYSTEM);
                if (w < 4) {
                    f32x4 zv = { 0.f, 0.f, 0.f, 0.f };
                    f32x4 ac0 = zv, ac1 = zv, ac2 = zv, ac3 = zv;
#pragma unroll
                    for (int kk = 0; kk < 32; kk += 4) {
#pragma unroll
                        for (int u = 0; u < 4; ++u) {
                            // A-frag: h[row][ (kk+u)*32 + hi*8 .. +8 ] from slice layout
                            int base = (2 * (kk + u) + (hi >> 1)) * 256 + row * 16 + (hi & 1) * 8;
                            bf16x8 a = *(const bf16x8*)(hstage + base);
                            f32x4& ac = (u == 0) ? ac0 : (u == 1) ? ac1 : (u == 2) ? ac2 : ac3;
                            ac = __builtin_amdgcn_mfma_f32_16x16x32_bf16(a, wf[kk + u], ac, 0, 0, 0);
                        }
                    }
                    f32x4 acc = (ac0 + ac1) + (ac2 + ac3);
#pragma unroll
                    for (int r = 0; r < 4; ++r)
                        zlds[w][hi * 4 + r][row] = acc[r];
                }
            }
            __syncthreads();       // B3: zlds ready; also guards hstage reuse next step
            if (tid < 256) {
                float zi = cz0, zf = cz1, zo = cz2, zc = cz3;
                if (t > 0) {
                    zi += zlds[0][b][hc]; zf += zlds[1][b][hc];
                    zo += zlds[2][b][hc]; zc += zlds[3][b][hc];
                }
                float ig = 1.f / (1.f + __expf(-zi));
                float fg = 1.f / (1.f + __expf(-zf));
                float og = 1.f / (1.f + __expf(-zo));
                float gg = tanhf(zc);
                cst = fg * cst + ig * gg;
                float h = og * tanhf(cst);
                float hn = __shfl_xor(h, 1);
                if (!(l & 1)) {
                    unsigned pk = (unsigned)f2bf(h) | ((unsigned)f2bf(hn) << 16);
                    u32* dst = (u32*)hs + (((size_t)(t * 16 + b) * 1024 + j * 16 + hc) >> 1);
                    __hip_atomic_store(dst, pk, __ATOMIC_RELAXED, __HIP_MEMORY_SCOPE_SYSTEM);
                }
                cz0 = nz0; cz1 = nz1; cz2 = nz2; cz3 = nz3;
            }
            if (w < 4) {
                asm volatile("s_waitcnt vmcnt(0)" ::: "memory");
                if (l == 0) {
                    u32 old = atomicAdd(lds_cnt, 1u);
                    if (old == (u32)(4 * t + 3))
                        __hip_atomic_store(&flags[(size_t)(t * 64 + j) * FLAG_STRIDE], 1u,
                                           __ATOMIC_RELAXED, __HIP_MEMORY_SCOPE_SYSTEM);
                }
            }
        }
        // final: confirm step 127 globally, then epoch = 128
        if (w == 0) {
            int spins = 0;
            while (true) {
                u32 f = __hip_atomic_load(&flags[(size_t)(127 * 64 + l) * FLAG_STRIDE],
                                          __ATOMIC_RELAXED, __HIP_MEMORY_SCOPE_SYSTEM);
                if (__ballot(f != 0) == ~0ull) break;
                __builtin_amdgcn_s_sleep(1);
                if (++spins > (1 << 20)) break;
            }
            if (l == 0)
                __hip_atomic_store(&flags[(size_t)(EPOCH_BASE + j) * FLAG_STRIDE], 128u,
                                   __ATOMIC_RELAXED, __HIP_MEMORY_SCOPE_SYSTEM);
        }
        return;
    }

    // ---------------- projection worker ----------------
    // Prologue: cooperative whqt transpose (hidden by n-outer slack). System-scope stores;
    // TCNT counter gates whqt reads. 2 tiles per block-iteration (one per 256-half).
    {
        float (*tp)[32][33] = (float (*)[32][33])(void*)smem;   // 8448 B
        const int half = tid >> 8, t256 = tid & 255;
        const int r = t256 >> 3, cq = (t256 & 7) * 4;
        const int c = t256 >> 3, rq = (t256 & 7) * 4;
        for (int it = 0; it < 84; ++it) {
            int q = it * 384 + (bx - 64) * 2 + half;
            bool act = q < 32000;
            int rt = 0, ct = 0;
            if (act) { rt = (q / 1000) * 32; ct = (q % 1000) * 32; }
            if (act) {
                float4 v = *(const float4*)(Whq + (size_t)(rt + r) * 32000 + ct + cq);
                tp[half][r][cq] = v.x; tp[half][r][cq + 1] = v.y;
                tp[half][r][cq + 2] = v.z; tp[half][r][cq + 3] = v.w;
            }
            __syncthreads();
            if (act) {
                u64 pk = (u64)f2bf(tp[half][rq][c])
                       | ((u64)f2bf(tp[half][rq + 1][c]) << 16)
                       | ((u64)f2bf(tp[half][rq + 2][c]) << 32)
                       | ((u64)f2bf(tp[half][rq + 3][c]) << 48);
                __hip_atomic_store((u64*)(whqt + (size_t)(ct + c) * 1024 + rt + rq), pk,
                                   __ATOMIC_RELAXED, __HIP_MEMORY_SCOPE_SYSTEM);
            }
            __syncthreads();
        }
        asm volatile("s_waitcnt vmcnt(0)" ::: "memory");
        if (tid == 0)
            __hip_atomic_fetch_add(&flags[(size_t)TCNT_BASE * FLAG_STRIDE], 1u,
                                   __ATOMIC_RELAXED, __HIP_MEMORY_SCOPE_SYSTEM);
    }

    u16* As = (u16*)smem;                   // 2 x 16 KB
    u16* Bs = (u16*)(smem + 32768);         // 2 x 32 KB
    u32* idx_slot = (u32*)(smem + 98304);
    const int wr = w >> 2, wc = w & 3;
    const int lr = l >> 4, lc = l & 15;

    // grab ONE n-tile for the whole run; wait for transpose completion (all 192 blocks)
    if (tid == 0)
        *idx_slot = __hip_atomic_fetch_add(&flags[(size_t)QCNT_BASE * FLAG_STRIDE],
                                           1u, __ATOMIC_RELAXED, __HIP_MEMORY_SCOPE_AGENT);
    if (w == 0) {
        int spins = 0;
        while (__hip_atomic_load(&flags[(size_t)TCNT_BASE * FLAG_STRIDE],
                                 __ATOMIC_RELAXED, __HIP_MEMORY_SCOPE_SYSTEM) < 192u) {
            __builtin_amdgcn_s_sleep(8);
            if (++spins > (1 << 20)) break;
        }
    }
    __syncthreads();
    const u32 myIdx = *idx_slot;
    if (myIdx >= NTILE) return;             // 67 surplus workers exit
    const int n0 = (int)myIdx * 256;

    for (int m = 0; m < 16; ++m) {
        if (w == 0) {                       // wait for t-chunk m readiness (one epoch line)
            const u32 need = (u32)(8 * m + 8);
            int spins = 0;
            while (__hip_atomic_load(&flags[(size_t)(EPOCH_BASE + (bx & 63)) * FLAG_STRIDE],
                                     __ATOMIC_RELAXED, __HIP_MEMORY_SCOPE_SYSTEM) < need) {
                __builtin_amdgcn_s_sleep(8);
                if (++spins > (1 << 20)) break;
            }
        }
        __syncthreads();

        auto STAGE = [&](int bi, int kt) {
#pragma unroll
            for (int i = 0; i < 2; ++i) {           // A: 128 rows x 8 chunks
                int C = i * 512 + tid, r = C >> 3, c = C & 7;
                int sc = c ^ (r & 7);
                int arow = (8 * m + (r & 7)) * 16 + (r >> 3);   // b-major within chunk
                gload_lds16(hs + (size_t)arow * 1024 + kt * 64 + sc * 8,
                            As + (size_t)(bi * 8192 + (i * 512 + w * 64) * 8));
            }
#pragma unroll
            for (int i = 0; i < 4; ++i) {           // B: 256 rows x 8 chunks
                int C = i * 512 + tid, r = C >> 3, c = C & 7;
                int sc = c ^ (r & 7);
                gload_lds16(whqt + (size_t)(n0 + r) * 1024 + kt * 64 + sc * 8,
                            Bs + (size_t)(bi * 16384 + (i * 512 + w * 64) * 8));
            }
        };

        f32x4 acc[4][4];
        f32x4 zz = { 0.f, 0.f, 0.f, 0.f };
#pragma unroll
        for (int i = 0; i < 4; i++)
#pragma unroll
            for (int jj = 0; jj < 4; jj++) acc[i][jj] = zz;

        int cur = 0;
        STAGE(0, 0);
        __syncthreads();
        for (int kt = 0; kt < 16; ++kt) {
            if (kt + 1 < 16) STAGE(cur ^ 1, kt + 1);
            const u16* Ab = As + cur * 8192;
            const u16* Bb = Bs + cur * 16384;
#pragma unroll
            for (int kk = 0; kk < 2; ++kk) {
                bf16x8 af[4], bf[4];
#pragma unroll
                for (int mi = 0; mi < 4; ++mi) {
                    int rA = wr * 64 + mi * 16 + lc;
                    int s = (kk * 4 + lr) ^ (rA & 7);
                    af[mi] = *(const bf16x8*)(Ab + rA * 64 + s * 8);
                }
#pragma unroll
                for (int ni = 0; ni < 4; ++ni) {
                    int rB = wc * 64 + ni * 16 + lc;
                    int s = (kk * 4 + lr) ^ (rB & 7);
                    bf[ni] = *(const bf16x8*)(Bb + rB * 64 + s * 8);
                }
#pragma unroll
                for (int mi = 0; mi < 4; ++mi)
#pragma unroll
                    for (int ni = 0; ni < 4; ++ni)
                        acc[mi][ni] = __builtin_amdgcn_mfma_f32_16x16x32_bf16(af[mi], bf[ni], acc[mi][ni], 0, 0, 0);
            }
            __syncthreads();   // drains vmcnt (next stage landed) + guards buf reuse
            cur ^= 1;
        }
#pragma unroll
        for (int ni = 0; ni < 4; ni++) {
            int col = n0 + wc * 64 + ni * 16 + lc;
            float bv = bq[col];
#pragma unroll
            for (int mi = 0; mi < 4; mi++) {
                int r0 = wr * 64 + mi * 16 + lr * 4;
                int bb = r0 >> 3;
                int t0 = 8 * m + (r0 & 7);
                float4 st = { acc[mi][ni][0] + bv, acc[mi][ni][1] + bv,
                              acc[mi][ni][2] + bv, acc[mi][ni][3] + bv };
                *(float4*)(out + (size_t)bb * 4096000 + (size_t)col * 128 + t0) = st;
            }
        }
    }
}

extern "C" void kernel_launch(void* const* d_in, const int* in_sizes, int n_in,
                              void* d_out, int out_size, void* d_ws, size_t ws_size,
                              hipStream_t stream) {
    const int*   sent = (const int*)d_in[0];
    const float* emb  = (const float*)d_in[1];
    const float* W_i  = (const float*)d_in[2];
    const float* b_i  = (const float*)d_in[3];
    const float* W_f  = (const float*)d_in[4];
    const float* b_f  = (const float*)d_in[5];
    const float* W_o  = (const float*)d_in[6];
    const float* b_o  = (const float*)d_in[7];
    const float* W_c  = (const float*)d_in[8];
    const float* b_c  = (const float*)d_in[9];
    const float* W_hq = (const float*)d_in[10];
    const float* b_q  = (const float*)d_in[11];
    float* out = (float*)d_out;

    char* ws = (char*)d_ws;
    size_t off = 0;
    auto alloc = [&](size_t bytes) { void* p = ws + off; off += (bytes + 255) & ~255ull; return p; };
    u32*   flags = (u32*)alloc((size_t)FLAG_WORDS * 4);
    float* b4   = (float*)alloc((size_t)4096 * 4);
    u16*   xb   = (u16*)alloc((size_t)2048 * 512 * 2);
    u16*   wxt  = (u16*)alloc((size_t)4096 * 512 * 2);
    u16*   hs   = (u16*)alloc((size_t)2048 * 1024 * 2);
    float* xz   = (float*)alloc((size_t)2048 * 4096 * 4);
    u16*   whqt = (u16*)alloc((size_t)32000 * 1024 * 2);

    hipMemsetAsync(flags, 0, (size_t)FLAG_WORDS * 4, stream);
    // prep: gather (1024) + b4 (16) + Wx transposes (2048)
    prep<<<3088, 256, 0, stream>>>(sent, emb, xb, b_i, b_f, b_o, b_c, b4,
                                   W_i, W_f, W_o, W_c, wxt);
    gemm_xz<<<dim3(16, 32), 256, 0, stream>>>(xb, wxt, b4, xz);
    // fused: 64 lstm blocks + 192 proj workers (whqt transpose in prologue, n-outer schedule)
    lstm_proj<<<256, 512, 0, stream>>>(hs, xz, W_i, W_f, W_o, W_c,
                                       flags, W_hq, whqt, b_q, out);
}

// Round 17
// 648.980 us; speedup vs baseline: 1.1338x; 1.0124x over previous
//
#include <hip/hip_runtime.h>
#include <math.h>

typedef float f32x4 __attribute__((ext_vector_type(4)));
typedef short bf16x8 __attribute__((ext_vector_type(8)));
typedef unsigned short u16;
typedef unsigned int u32;
typedef unsigned long long u64;

#define FLAG_STRIDE 16            // one u32 flag per 64B line
#define ACQ_BASE    8192          // 256 acquire-dummy lines (after 128*64 step flags)
#define EPOCH_BASE  8448          // 64 epoch lines
#define QCNT_BASE   8512          // n-tile queue (single line)
#define TCNT_BASE   8528          // whqt-transpose completion counter
#define FLAG_WORDS  ((TCNT_BASE + 1) * FLAG_STRIDE)
#define NTILE       125           // 32000 / 256 proj n-tiles

__device__ __forceinline__ u16 f2bf(float f) {
    union { float f; unsigned u; } x; x.f = f;
    unsigned r = x.u + 0x7fff + ((x.u >> 16) & 1);   // RNE
    return (u16)(r >> 16);
}

// async global->LDS, 16B/lane. LDS dest wave-uniform base; HW adds lane*16. Global src per-lane.
__device__ __forceinline__ void gload_lds16(const u16* g, u16* l) {
    __builtin_amdgcn_global_load_lds(
        (const __attribute__((address_space(1))) void*)g,
        (__attribute__((address_space(3))) void*)l, 16, 0, 0);
}

// ================= prep: embedding gather ONLY (Wx/b4/xz folded into fused kernel) ============
__global__ __launch_bounds__(256) void prep(
    const int* __restrict__ sent, const float* __restrict__ emb, u16* __restrict__ xb) {
    const int bx = blockIdx.x, tid = threadIdx.x;
    int row = bx * 2 + (tid >> 7);     // t*16+b
    int t = row >> 4, b = row & 15;
    int idx = sent[b * 128 + t];
    float4 v = ((const float4*)(emb + (size_t)idx * 512))[tid & 127];
    ushort4 s = { f2bf(v.x), f2bf(v.y), f2bf(v.z), f2bf(v.w) };
    ((ushort4*)(xb + (size_t)row * 512))[tid & 127] = s;
}

// ================= fused: LSTM (blocks 0..63) + proj workers (64..255), 512thr, 1 block/CU =====
// lstm: r11-proven sync protocol (distributed GROUP poll + full-wave slice staging), PLUS
//   on-the-fly x-projection: Wx B-frags (4 gates x K=512 x 16 cols) in 64KB LDS (loaded once),
//   x_t staged per step in hstage-style slice layout (double-buffered, issued at step top ->
//   off the inter-WG critical path), 16 extra MFMAs/gate-wave into the same accumulator.
//   Replaces the xz GEMM + xz buffer + per-step xz prefetch entirely.
// proj: r16 champion (whqt transpose prologue, ONE n-tile per worker, m-sweep 0..15).
__global__ __launch_bounds__(512, 2) void lstm_proj(
    u16* __restrict__ hs,          // [128*16][1024] bf16, row = t*16+b
    const u16* __restrict__ xb,    // [128*16][512] bf16 embedded input
    const float* __restrict__ Wi, const float* __restrict__ Wf,
    const float* __restrict__ Wo, const float* __restrict__ Wc,
    const float* __restrict__ bi, const float* __restrict__ bf_,
    const float* __restrict__ bo, const float* __restrict__ bc,
    u32* __restrict__ flags,
    const float* __restrict__ Whq, // [1024][32000] f32 (source)
    u16* __restrict__ whqt,        // [32000][1024] bf16 (transposed here)
    const float* __restrict__ bq, float* __restrict__ out) {
    __shared__ __align__(16) char smem[135680];   // >81920 -> exactly 1 block/CU
    const int bx = blockIdx.x;
    const int tid = threadIdx.x;
    const int w = tid >> 6, l = tid & 63;

    // one-time cache invalidate (cross-replay staleness in L1/L2)
    if (tid == 0)
        __hip_atomic_fetch_add(&flags[(size_t)(ACQ_BASE + (bx & 255)) * FLAG_STRIDE], 0u,
                               __ATOMIC_ACQ_REL, __HIP_MEMORY_SCOPE_AGENT);

    if (bx < 64) {
        // ---------------- LSTM path ----------------
        u16* hstage = (u16*)smem;                              // 32 KB: [jw=64][b=16][2x16B]
        u16* xstage = (u16*)(smem + 32768);                    // 2 x 16 KB: [jx=32][b=16][2x16B]
        u16* wfx    = (u16*)(smem + 65536);                    // 64 KB: [gate][kk=16][lane][8]
        float (*zlds)[16][17] = (float (*)[16][17])(void*)(smem + 131072);  // 4352 B
        u32* lds_cnt = (u32*)(smem + 135424);
        const int j = bx;
        const int row = l & 15, hi = l >> 4;
        if (tid == 0) *lds_cnt = 0;

        // W_h B-frags in registers (rows 512..1535) + Wx B-frags in LDS (rows 0..511)
        bf16x8 wf[32];
        if (w < 4) {
            const float* Wg = (w == 0) ? Wi : (w == 1) ? Wf : (w == 2) ? Wo : Wc;
#pragma unroll
            for (int kk = 0; kk < 32; ++kk)
#pragma unroll
                for (int e = 0; e < 8; ++e)
                    wf[kk][e] = f2bf(Wg[(size_t)(512 + kk * 32 + hi * 8 + e) * 1024 + j * 16 + row]);
#pragma unroll
            for (int kk = 0; kk < 16; ++kk) {
                bf16x8 v;
#pragma unroll
                for (int e = 0; e < 8; ++e)
                    v[e] = f2bf(Wg[(size_t)(kk * 32 + hi * 8 + e) * 1024 + j * 16 + row]);
                *(bf16x8*)(wfx + ((size_t)(w * 16 + kk) * 64 + l) * 8) = v;
            }
        }
        // per-thread gate biases
        float bzi = 0.f, bzf = 0.f, bzo = 0.f, bzc = 0.f;
        const int b = tid >> 4, hc = tid & 15;
        if (tid < 256) {
            bzi = bi[j * 16 + hc]; bzf = bf_[j * 16 + hc];
            bzo = bo[j * 16 + hc]; bzc = bc[j * 16 + hc];
        }
        // stage x_0 into xbuf[0] (16 full-wave 1KB loads, 2 per wave)
#pragma unroll
        for (int q = 0; q < 2; ++q) {
            int jx0 = (w * 2 + q) * 2;
            gload_lds16(xb + (size_t)((l & 31) >> 1) * 512 + (jx0 + (l >> 5)) * 16 + (l & 1) * 8,
                        xstage + (size_t)jx0 * 256);
        }
        __syncthreads();   // wfx visible to all (x_0 drains at B2 of t=0)

        float cst = 0.f;

        for (int t = 0; t < 128; ++t) {
            // ---- issue x_{t+1} stage EARLY (static data: overlaps the flag wait)
            if (t < 127) {
                const u16* xbase = xb + (size_t)(t + 1) * 16 * 512;
                u16* xd = xstage + ((t + 1) & 1) * 8192;
#pragma unroll
                for (int q = 0; q < 2; ++q) {
                    int jx0 = (w * 2 + q) * 2;
                    gload_lds16(xbase + (size_t)((l & 31) >> 1) * 512 + (jx0 + (l >> 5)) * 16 + (l & 1) * 8,
                                xd + (size_t)jx0 * 256);
                }
            }
            if (t > 0) {
                const u16* hbase = hs + (size_t)(t - 1) * 16 * 1024;
                // ---- confirm ALL 8 source flags for this wave (lanes 0-7 poll in parallel)
                {
                    int spins = 0;
                    while (true) {
                        u32 f = 1u;
                        if (l < 8)
                            f = __hip_atomic_load(
                                    &flags[(size_t)((t - 1) * 64 + 8 * w + l) * FLAG_STRIDE],
                                    __ATOMIC_RELAXED, __HIP_MEMORY_SCOPE_SYSTEM);
                        if (__ballot(f != 0u) == ~0ull) break;
                        __builtin_amdgcn_s_sleep(1);
                        if (++spins > (1 << 20)) break;   // safety bail
                    }
                }
                // ---- THEN stage the 8 slices: 4 full-wave 1KB loads (2 slices each)
#pragma unroll
                for (int q = 0; q < 4; ++q) {
                    int jw0 = 8 * w + 2 * q;
                    gload_lds16(hbase + (size_t)((l & 31) >> 1) * 1024
                                      + (jw0 + (l >> 5)) * 16 + (l & 1) * 8,
                                hstage + (size_t)jw0 * 256);
                }
            }
            __syncthreads();   // B2: vmcnt drain -> h slices + x_t (+wfx at t=0) in LDS
            {
                if (t > 0 && tid == 0)  // all flags of t-1 confirmed block-wide -> epoch
                    __hip_atomic_store(&flags[(size_t)(EPOCH_BASE + j) * FLAG_STRIDE], (u32)t,
                                       __ATOMIC_RELAXED, __HIP_MEMORY_SCOPE_SYSTEM);
                if (w < 4) {
                    const u16* xs = xstage + (t & 1) * 8192;
                    f32x4 zv = { 0.f, 0.f, 0.f, 0.f };
                    f32x4 ac0 = zv, ac1 = zv, ac2 = zv, ac3 = zv;
                    // x-part: z_x = x_t @ Wx_slice (K=512, 16 MFMAs)
#pragma unroll
                    for (int kk = 0; kk < 16; kk += 4) {
#pragma unroll
                        for (int u = 0; u < 4; ++u) {
                            int c = kk + u;
                            bf16x8 a = *(const bf16x8*)(xs + (2 * c + (hi >> 1)) * 256
                                                        + row * 16 + (hi & 1) * 8);
                            bf16x8 bx = *(const bf16x8*)(wfx + ((size_t)(w * 16 + c) * 64 + l) * 8);
                            f32x4& ac = (u == 0) ? ac0 : (u == 1) ? ac1 : (u == 2) ? ac2 : ac3;
                            ac = __builtin_amdgcn_mfma_f32_16x16x32_bf16(a, bx, ac, 0, 0, 0);
                        }
                    }
                    // h-part: z_h = h_{t-1} @ Wh_slice (K=1024, 32 MFMAs)
                    if (t > 0) {
#pragma unroll
                        for (int kk = 0; kk < 32; kk += 4) {
#pragma unroll
                            for (int u = 0; u < 4; ++u) {
                                int c = kk + u;
                                int base = (2 * c + (hi >> 1)) * 256 + row * 16 + (hi & 1) * 8;
                                bf16x8 a = *(const bf16x8*)(hstage + base);
                                f32x4& ac = (u == 0) ? ac0 : (u == 1) ? ac1 : (u == 2) ? ac2 : ac3;
                                ac = __builtin_amdgcn_mfma_f32_16x16x32_bf16(a, wf[c], ac, 0, 0, 0);
                            }
                        }
                    }
                    f32x4 acc = (ac0 + ac1) + (ac2 + ac3);
#pragma unroll
                    for (int r = 0; r < 4; ++r)
                        zlds[w][hi * 4 + r][row] = acc[r];
                }
            }
            __syncthreads();       // B3: zlds ready; guards hstage/xstage reuse
            if (tid < 256) {
                float zi = zlds[0][b][hc] + bzi;
                float zf = zlds[1][b][hc] + bzf;
                float zo = zlds[2][b][hc] + bzo;
                float zc = zlds[3][b][hc] + bzc;
                float ig = 1.f / (1.f + __expf(-zi));
                float fg = 1.f / (1.f + __expf(-zf));
                float og = 1.f / (1.f + __expf(-zo));
                float gg = tanhf(zc);
                cst = fg * cst + ig * gg;
                float h = og * tanhf(cst);
                float hn = __shfl_xor(h, 1);
                if (!(l & 1)) {
                    unsigned pk = (unsigned)f2bf(h) | ((unsigned)f2bf(hn) << 16);
                    u32* dst = (u32*)hs + (((size_t)(t * 16 + b) * 1024 + j * 16 + hc) >> 1);
                    __hip_atomic_store(dst, pk, __ATOMIC_RELAXED, __HIP_MEMORY_SCOPE_SYSTEM);
                }
            }
            if (w < 4) {
                asm volatile("s_waitcnt vmcnt(0)" ::: "memory");
                if (l == 0) {
                    u32 old = atomicAdd(lds_cnt, 1u);
                    if (old == (u32)(4 * t + 3))
                        __hip_atomic_store(&flags[(size_t)(t * 64 + j) * FLAG_STRIDE], 1u,
                                           __ATOMIC_RELAXED, __HIP_MEMORY_SCOPE_SYSTEM);
                }
            }
        }
        // final: confirm step 127 globally, then epoch = 128
        if (w == 0) {
            int spins = 0;
            while (true) {
                u32 f = __hip_atomic_load(&flags[(size_t)(127 * 64 + l) * FLAG_STRIDE],
                                          __ATOMIC_RELAXED, __HIP_MEMORY_SCOPE_SYSTEM);
                if (__ballot(f != 0) == ~0ull) break;
                __builtin_amdgcn_s_sleep(1);
                if (++spins > (1 << 20)) break;
            }
            if (l == 0)
                __hip_atomic_store(&flags[(size_t)(EPOCH_BASE + j) * FLAG_STRIDE], 128u,
                                   __ATOMIC_RELAXED, __HIP_MEMORY_SCOPE_SYSTEM);
        }
        return;
    }

    // ---------------- projection worker ----------------
    // Prologue: cooperative whqt transpose (hidden by n-outer slack). System-scope stores;
    // TCNT counter gates whqt reads.
    {
        float (*tp)[32][33] = (float (*)[32][33])(void*)smem;   // 8448 B
        const int half = tid >> 8, t256 = tid & 255;
        const int r = t256 >> 3, cq = (t256 & 7) * 4;
        const int c = t256 >> 3, rq = (t256 & 7) * 4;
        for (int it = 0; it < 84; ++it) {
            int q = it * 384 + (bx - 64) * 2 + half;
            bool act = q < 32000;
            int rt = 0, ct = 0;
            if (act) { rt = (q / 1000) * 32; ct = (q % 1000) * 32; }
            if (act) {
                float4 v = *(const float4*)(Whq + (size_t)(rt + r) * 32000 + ct + cq);
                tp[half][r][cq] = v.x; tp[half][r][cq + 1] = v.y;
                tp[half][r][cq + 2] = v.z; tp[half][r][cq + 3] = v.w;
            }
            __syncthreads();
            if (act) {
                u64 pk = (u64)f2bf(tp[half][rq][c])
                       | ((u64)f2bf(tp[half][rq + 1][c]) << 16)
                       | ((u64)f2bf(tp[half][rq + 2][c]) << 32)
                       | ((u64)f2bf(tp[half][rq + 3][c]) << 48);
                __hip_atomic_store((u64*)(whqt + (size_t)(ct + c) * 1024 + rt + rq), pk,
                                   __ATOMIC_RELAXED, __HIP_MEMORY_SCOPE_SYSTEM);
            }
            __syncthreads();
        }
        asm volatile("s_waitcnt vmcnt(0)" ::: "memory");
        if (tid == 0)
            __hip_atomic_fetch_add(&flags[(size_t)TCNT_BASE * FLAG_STRIDE], 1u,
                                   __ATOMIC_RELAXED, __HIP_MEMORY_SCOPE_SYSTEM);
    }

    u16* As = (u16*)smem;                   // 2 x 16 KB
    u16* Bs = (u16*)(smem + 32768);         // 2 x 32 KB
    u32* idx_slot = (u32*)(smem + 98304);
    const int wr = w >> 2, wc = w & 3;
    const int lr = l >> 4, lc = l & 15;

    // grab ONE n-tile for the whole run; wait for transpose completion (all 192 blocks)
    if (tid == 0)
        *idx_slot = __hip_atomic_fetch_add(&flags[(size_t)QCNT_BASE * FLAG_STRIDE],
                                           1u, __ATOMIC_RELAXED, __HIP_MEMORY_SCOPE_AGENT);
    if (w == 0) {
        int spins = 0;
        while (__hip_atomic_load(&flags[(size_t)TCNT_BASE * FLAG_STRIDE],
                                 __ATOMIC_RELAXED, __HIP_MEMORY_SCOPE_SYSTEM) < 192u) {
            __builtin_amdgcn_s_sleep(8);
            if (++spins > (1 << 20)) break;
        }
    }
    __syncthreads();
    const u32 myIdx = *idx_slot;
    if (myIdx >= NTILE) return;             // 67 surplus workers exit
    const int n0 = (int)myIdx * 256;

    for (int m = 0; m < 16; ++m) {
        if (w == 0) {                       // wait for t-chunk m readiness (one epoch line)
            const u32 need = (u32)(8 * m + 8);
            int spins = 0;
            while (__hip_atomic_load(&flags[(size_t)(EPOCH_BASE + (bx & 63)) * FLAG_STRIDE],
                                     __ATOMIC_RELAXED, __HIP_MEMORY_SCOPE_SYSTEM) < need) {
                __builtin_amdgcn_s_sleep(8);
                if (++spins > (1 << 20)) break;
            }
        }
        __syncthreads();

        auto STAGE = [&](int bi, int kt) {
#pragma unroll
            for (int i = 0; i < 2; ++i) {           // A: 128 rows x 8 chunks
                int C = i * 512 + tid, r = C >> 3, c = C & 7;
                int sc = c ^ (r & 7);
                int arow = (8 * m + (r & 7)) * 16 + (r >> 3);   // b-major within chunk
                gload_lds16(hs + (size_t)arow * 1024 + kt * 64 + sc * 8,
                            As + (size_t)(bi * 8192 + (i * 512 + w * 64) * 8));
            }
#pragma unroll
            for (int i = 0; i < 4; ++i) {           // B: 256 rows x 8 chunks
                int C = i * 512 + tid, r = C >> 3, c = C & 7;
                int sc = c ^ (r & 7);
                gload_lds16(whqt + (size_t)(n0 + r) * 1024 + kt * 64 + sc * 8,
                            Bs + (size_t)(bi * 16384 + (i * 512 + w * 64) * 8));
            }
        };

        f32x4 acc[4][4];
        f32x4 zz = { 0.f, 0.f, 0.f, 0.f };
#pragma unroll
        for (int i = 0; i < 4; i++)
#pragma unroll
            for (int jj = 0; jj < 4; jj++) acc[i][jj] = zz;

        int cur = 0;
        STAGE(0, 0);
        __syncthreads();
        for (int kt = 0; kt < 16; ++kt) {
            if (kt + 1 < 16) STAGE(cur ^ 1, kt + 1);
            const u16* Ab = As + cur * 8192;
            const u16* Bb = Bs + cur * 16384;
#pragma unroll
            for (int kk = 0; kk < 2; ++kk) {
                bf16x8 af[4], bf[4];
#pragma unroll
                for (int mi = 0; mi < 4; ++mi) {
                    int rA = wr * 64 + mi * 16 + lc;
                    int s = (kk * 4 + lr) ^ (rA & 7);
                    af[mi] = *(const bf16x8*)(Ab + rA * 64 + s * 8);
                }
#pragma unroll
                for (int ni = 0; ni < 4; ++ni) {
                    int rB = wc * 64 + ni * 16 + lc;
                    int s = (kk * 4 + lr) ^ (rB & 7);
                    bf[ni] = *(const bf16x8*)(Bb + rB * 64 + s * 8);
                }
#pragma unroll
                for (int mi = 0; mi < 4; ++mi)
#pragma unroll
                    for (int ni = 0; ni < 4; ++ni)
                        acc[mi][ni] = __builtin_amdgcn_mfma_f32_16x16x32_bf16(af[mi], bf[ni], acc[mi][ni], 0, 0, 0);
            }
            __syncthreads();   // drains vmcnt (next stage landed) + guards buf reuse
            cur ^= 1;
        }
#pragma unroll
        for (int ni = 0; ni < 4; ni++) {
            int col = n0 + wc * 64 + ni * 16 + lc;
            float bv = bq[col];
#pragma unroll
            for (int mi = 0; mi < 4; mi++) {
                int r0 = wr * 64 + mi * 16 + lr * 4;
                int bb = r0 >> 3;
                int t0 = 8 * m + (r0 & 7);
                float4 st = { acc[mi][ni][0] + bv, acc[mi][ni][1] + bv,
                              acc[mi][ni][2] + bv, acc[mi][ni][3] + bv };
                *(float4*)(out + (size_t)bb * 4096000 + (size_t)col * 128 + t0) = st;
            }
        }
    }
}

extern "C" void kernel_launch(void* const* d_in, const int* in_sizes, int n_in,
                              void* d_out, int out_size, void* d_ws, size_t ws_size,
                              hipStream_t stream) {
    const int*   sent = (const int*)d_in[0];
    const float* emb  = (const float*)d_in[1];
    const float* W_i  = (const float*)d_in[2];
    const float* b_i  = (const float*)d_in[3];
    const float* W_f  = (const float*)d_in[4];
    const float* b_f  = (const float*)d_in[5];
    const float* W_o  = (const float*)d_in[6];
    const float* b_o  = (const float*)d_in[7];
    const float* W_c  = (const float*)d_in[8];
    const float* b_c  = (const float*)d_in[9];
    const float* W_hq = (const float*)d_in[10];
    const float* b_q  = (const float*)d_in[11];
    float* out = (float*)d_out;

    char* ws = (char*)d_ws;
    size_t off = 0;
    auto alloc = [&](size_t bytes) { void* p = ws + off; off += (bytes + 255) & ~255ull; return p; };
    u32*   flags = (u32*)alloc((size_t)FLAG_WORDS * 4);
    u16*   xb   = (u16*)alloc((size_t)2048 * 512 * 2);
    u16*   hs   = (u16*)alloc((size_t)2048 * 1024 * 2);
    u16*   whqt = (u16*)alloc((size_t)32000 * 1024 * 2);

    hipMemsetAsync(flags, 0, (size_t)FLAG_WORDS * 4, stream);
    // prep: embedding gather only
    prep<<<1024, 256, 0, stream>>>(sent, emb, xb);
    // fused: 64 lstm blocks (with on-the-fly x-projection) + 192 proj workers
    lstm_proj<<<256, 512, 0, stream>>>(hs, xb, W_i, W_f, W_o, W_c,
                                       b_i, b_f, b_o, b_c,
                                       flags, W_hq, whqt, b_q, out);
}

// Round 18
// 632.221 us; speedup vs baseline: 1.1638x; 1.0265x over previous
//
#include <hip/hip_runtime.h>
#include <math.h>

typedef float f32x4 __attribute__((ext_vector_type(4)));
typedef short bf16x8 __attribute__((ext_vector_type(8)));
typedef unsigned short u16;
typedef unsigned int u32;
typedef unsigned long long u64;

#define FLAG_STRIDE 16            // one u32 flag per 64B line
#define ACQ_BASE    8192          // 256 acquire-dummy lines (after 128*64 step flags)
#define EPOCH_BASE  8448          // 64 epoch lines
#define QCNT_BASE   8512          // n-tile queue (single line)
#define TCNT_BASE   8528          // whqt-transpose completion counter
#define FLAG_WORDS  ((TCNT_BASE + 1) * FLAG_STRIDE)
#define NTILE       125           // 32000 / 256 proj n-tiles

__device__ __forceinline__ u16 f2bf(float f) {
    union { float f; unsigned u; } x; x.f = f;
    unsigned r = x.u + 0x7fff + ((x.u >> 16) & 1);   // RNE
    return (u16)(r >> 16);
}

// async global->LDS, 16B/lane. LDS dest wave-uniform base; HW adds lane*16. Global src per-lane.
__device__ __forceinline__ void gload_lds16(const u16* g, u16* l) {
    __builtin_amdgcn_global_load_lds(
        (const __attribute__((address_space(1))) void*)g,
        (__attribute__((address_space(3))) void*)l, 16, 0, 0);
}

// ================= prep: embedding gather ONLY ============
__global__ __launch_bounds__(256) void prep(
    const int* __restrict__ sent, const float* __restrict__ emb, u16* __restrict__ xb) {
    const int bx = blockIdx.x, tid = threadIdx.x;
    int row = bx * 2 + (tid >> 7);     // t*16+b
    int t = row >> 4, b = row & 15;
    int idx = sent[b * 128 + t];
    float4 v = ((const float4*)(emb + (size_t)idx * 512))[tid & 127];
    ushort4 s = { f2bf(v.x), f2bf(v.y), f2bf(v.z), f2bf(v.w) };
    ((ushort4*)(xb + (size_t)row * 512))[tid & 127] = s;
}

// ================= fused: LSTM (blocks 0..63) + proj workers (64..255), 512thr, 1 block/CU =====
// lstm (THIS ROUND — wave role split):
//   waves 4-7 (readers): own ALL flag polling (wave 4+k: 16 flags via lanes 0-15, 512B-aligned
//     group -> line-race-safe) + ALL h staging (8 full-wave 1KB loads each) + x staging (2 steps
//     ahead, double-buffered). Their poll starts right after B3 -> detection overlaps writers'
//     store chain.
//   waves 0-3 (writers): gates/store/publish, then compute zx_next = x_{t+1}@Wx (16 MFMAs,
//     operands drained >=1 step ago) WHILE readers poll -> B2->B3 shrinks to 32 h-MFMAs
//     starting from acc = zx_cur.
// proj: r16/r17 champion (whqt transpose prologue, ONE n-tile per worker, m-sweep 0..15).
__global__ __launch_bounds__(512, 2) void lstm_proj(
    u16* __restrict__ hs,          // [128*16][1024] bf16, row = t*16+b
    const u16* __restrict__ xb,    // [128*16][512] bf16 embedded input
    const float* __restrict__ Wi, const float* __restrict__ Wf,
    const float* __restrict__ Wo, const float* __restrict__ Wc,
    const float* __restrict__ bi, const float* __restrict__ bf_,
    const float* __restrict__ bo, const float* __restrict__ bc,
    u32* __restrict__ flags,
    const float* __restrict__ Whq, // [1024][32000] f32 (source)
    u16* __restrict__ whqt,        // [32000][1024] bf16 (transposed here)
    const float* __restrict__ bq, float* __restrict__ out) {
    __shared__ __align__(16) char smem[135680];   // >81920 -> exactly 1 block/CU
    const int bx = blockIdx.x;
    const int tid = threadIdx.x;
    const int w = tid >> 6, l = tid & 63;

    // one-time cache invalidate (cross-replay staleness in L1/L2)
    if (tid == 0)
        __hip_atomic_fetch_add(&flags[(size_t)(ACQ_BASE + (bx & 255)) * FLAG_STRIDE], 0u,
                               __ATOMIC_ACQ_REL, __HIP_MEMORY_SCOPE_AGENT);

    if (bx < 64) {
        // ---------------- LSTM path ----------------
        u16* hstage = (u16*)smem;                              // 32 KB: [jw=64][b=16][2x16B]
        u16* xstage = (u16*)(smem + 32768);                    // 2 x 16 KB: [jx=32][b=16][2x16B]
        u16* wfx    = (u16*)(smem + 65536);                    // 64 KB: [gate][kk=16][lane][8]
        float (*zlds)[16][17] = (float (*)[16][17])(void*)(smem + 131072);  // 4352 B
        u32* lds_cnt = (u32*)(smem + 135424);
        const int j = bx;
        const int row = l & 15, hi = l >> 4;
        if (tid == 0) *lds_cnt = 0;

        // W_h B-frags in registers (rows 512..1535) + Wx B-frags in LDS (rows 0..511)
        bf16x8 wf[32];
        if (w < 4) {
            const float* Wg = (w == 0) ? Wi : (w == 1) ? Wf : (w == 2) ? Wo : Wc;
#pragma unroll
            for (int kk = 0; kk < 32; ++kk)
#pragma unroll
                for (int e = 0; e < 8; ++e)
                    wf[kk][e] = f2bf(Wg[(size_t)(512 + kk * 32 + hi * 8 + e) * 1024 + j * 16 + row]);
#pragma unroll
            for (int kk = 0; kk < 16; ++kk) {
                bf16x8 v;
#pragma unroll
                for (int e = 0; e < 8; ++e)
                    v[e] = f2bf(Wg[(size_t)(kk * 32 + hi * 8 + e) * 1024 + j * 16 + row]);
                *(bf16x8*)(wfx + ((size_t)(w * 16 + kk) * 64 + l) * 8) = v;
            }
        } else {
            // readers: stage x0 -> xbuf[0], x1 -> xbuf[1]
#pragma unroll
            for (int q = 0; q < 4; ++q) {
                int jx0 = ((w - 4) * 4 + q) * 2;
                gload_lds16(xb + (size_t)((l & 31) >> 1) * 512 + (jx0 + (l >> 5)) * 16 + (l & 1) * 8,
                            xstage + (size_t)jx0 * 256);
            }
#pragma unroll
            for (int q = 0; q < 4; ++q) {
                int jx0 = ((w - 4) * 4 + q) * 2;
                gload_lds16(xb + (size_t)(16 * 512 + ((l & 31) >> 1) * 512) + (jx0 + (l >> 5)) * 16 + (l & 1) * 8,
                            xstage + (size_t)(8192 + jx0 * 256));
            }
        }
        // per-thread gate biases
        float bzi = 0.f, bzf = 0.f, bzo = 0.f, bzc = 0.f;
        const int b = tid >> 4, hc = tid & 15;
        if (tid < 256) {
            bzi = bi[j * 16 + hc]; bzf = bf_[j * 16 + hc];
            bzo = bo[j * 16 + hc]; bzc = bc[j * 16 + hc];
        }
        __syncthreads();   // x0,x1 drained; wfx visible

        // zx_cur for t=0 (from xbuf[0])
        f32x4 zz4 = { 0.f, 0.f, 0.f, 0.f };
        f32x4 zxc0 = zz4, zxc1 = zz4, zxc2 = zz4, zxc3 = zz4;
        if (w < 4) {
#pragma unroll
            for (int kk = 0; kk < 16; kk += 4) {
#pragma unroll
                for (int u = 0; u < 4; ++u) {
                    int c = kk + u;
                    bf16x8 a = *(const bf16x8*)(xstage + (2 * c + (hi >> 1)) * 256
                                                + row * 16 + (hi & 1) * 8);
                    bf16x8 bxv = *(const bf16x8*)(wfx + ((size_t)(w * 16 + c) * 64 + l) * 8);
                    f32x4& ac = (u == 0) ? zxc0 : (u == 1) ? zxc1 : (u == 2) ? zxc2 : zxc3;
                    ac = __builtin_amdgcn_mfma_f32_16x16x32_bf16(a, bxv, ac, 0, 0, 0);
                }
            }
        }
        float cst = 0.f;

        for (int t = 0; t < 128; ++t) {
            f32x4 zxn0 = zz4, zxn1 = zz4, zxn2 = zz4, zxn3 = zz4;
            if (w >= 4) {
                // ---- readers: issue x_{t+2} stage into xbuf[t&1]
                if (t < 126) {
                    const u16* xbase = xb + (size_t)(t + 2) * 16 * 512;
                    u16* xd = xstage + (t & 1) * 8192;
#pragma unroll
                    for (int q = 0; q < 4; ++q) {
                        int jx0 = ((w - 4) * 4 + q) * 2;
                        gload_lds16(xbase + (size_t)((l & 31) >> 1) * 512 + (jx0 + (l >> 5)) * 16 + (l & 1) * 8,
                                    xd + (size_t)jx0 * 256);
                    }
                }
                if (t > 0) {
                    // ---- poll this wave's 16 source flags (lanes 0-15), 512B-aligned group
                    {
                        int spins = 0;
                        while (true) {
                            u32 f = 1u;
                            if (l < 16)
                                f = __hip_atomic_load(
                                        &flags[(size_t)((t - 1) * 64 + (w - 4) * 16 + l) * FLAG_STRIDE],
                                        __ATOMIC_RELAXED, __HIP_MEMORY_SCOPE_SYSTEM);
                            if (__ballot(f != 0u) == ~0ull) break;
                            __builtin_amdgcn_s_sleep(1);
                            if (++spins > (1 << 20)) break;   // safety bail
                        }
                    }
                    // ---- stage the 16 slices: 8 full-wave 1KB loads (2 slices each)
                    const u16* hbase = hs + (size_t)(t - 1) * 16 * 1024;
#pragma unroll
                    for (int q = 0; q < 8; ++q) {
                        int jw0 = (w - 4) * 16 + 2 * q;
                        gload_lds16(hbase + (size_t)((l & 31) >> 1) * 1024
                                          + (jw0 + (l >> 5)) * 16 + (l & 1) * 8,
                                    hstage + (size_t)jw0 * 256);
                    }
                }
            } else {
                // ---- writers: compute zx_next = x_{t+1} @ Wx (operands drained >=1 step ago)
                if (t < 127) {
                    const u16* xs = xstage + ((t + 1) & 1) * 8192;
#pragma unroll
                    for (int kk = 0; kk < 16; kk += 4) {
#pragma unroll
                        for (int u = 0; u < 4; ++u) {
                            int c = kk + u;
                            bf16x8 a = *(const bf16x8*)(xs + (2 * c + (hi >> 1)) * 256
                                                        + row * 16 + (hi & 1) * 8);
                            bf16x8 bxv = *(const bf16x8*)(wfx + ((size_t)(w * 16 + c) * 64 + l) * 8);
                            f32x4& ac = (u == 0) ? zxn0 : (u == 1) ? zxn1 : (u == 2) ? zxn2 : zxn3;
                            ac = __builtin_amdgcn_mfma_f32_16x16x32_bf16(a, bxv, ac, 0, 0, 0);
                        }
                    }
                }
            }
            __syncthreads();   // B2: h slices (+x stage) drained -> LDS consistent
            if (t > 0 && tid == 0)   // all flags of t-1 confirmed block-wide -> epoch
                __hip_atomic_store(&flags[(size_t)(EPOCH_BASE + j) * FLAG_STRIDE], (u32)t,
                                   __ATOMIC_RELAXED, __HIP_MEMORY_SCOPE_SYSTEM);
            if (w < 4) {
                f32x4 ac0 = zxc0, ac1 = zxc1, ac2 = zxc2, ac3 = zxc3;
                if (t > 0) {
#pragma unroll
                    for (int kk = 0; kk < 32; kk += 4) {
#pragma unroll
                        for (int u = 0; u < 4; ++u) {
                            int c = kk + u;
                            int base = (2 * c + (hi >> 1)) * 256 + row * 16 + (hi & 1) * 8;
                            bf16x8 a = *(const bf16x8*)(hstage + base);
                            f32x4& ac = (u == 0) ? ac0 : (u == 1) ? ac1 : (u == 2) ? ac2 : ac3;
                            ac = __builtin_amdgcn_mfma_f32_16x16x32_bf16(a, wf[c], ac, 0, 0, 0);
                        }
                    }
                }
                f32x4 acc = (ac0 + ac1) + (ac2 + ac3);
#pragma unroll
                for (int r = 0; r < 4; ++r)
                    zlds[w][hi * 4 + r][row] = acc[r];
            }
            __syncthreads();       // B3: zlds ready; guards hstage/xstage reuse
            if (tid < 256) {
                float zi = zlds[0][b][hc] + bzi;
                float zf = zlds[1][b][hc] + bzf;
                float zo = zlds[2][b][hc] + bzo;
                float zc = zlds[3][b][hc] + bzc;
                float ig = 1.f / (1.f + __expf(-zi));
                float fg = 1.f / (1.f + __expf(-zf));
                float og = 1.f / (1.f + __expf(-zo));
                float gg = tanhf(zc);
                cst = fg * cst + ig * gg;
                float h = og * tanhf(cst);
                float hn = __shfl_xor(h, 1);
                if (!(l & 1)) {
                    unsigned pk = (unsigned)f2bf(h) | ((unsigned)f2bf(hn) << 16);
                    u32* dst = (u32*)hs + (((size_t)(t * 16 + b) * 1024 + j * 16 + hc) >> 1);
                    __hip_atomic_store(dst, pk, __ATOMIC_RELAXED, __HIP_MEMORY_SCOPE_SYSTEM);
                }
            }
            if (w < 4) {
                asm volatile("s_waitcnt vmcnt(0)" ::: "memory");
                if (l == 0) {
                    u32 old = atomicAdd(lds_cnt, 1u);
                    if (old == (u32)(4 * t + 3))
                        __hip_atomic_store(&flags[(size_t)(t * 64 + j) * FLAG_STRIDE], 1u,
                                           __ATOMIC_RELAXED, __HIP_MEMORY_SCOPE_SYSTEM);
                }
                zxc0 = zxn0; zxc1 = zxn1; zxc2 = zxn2; zxc3 = zxn3;
            }
        }
        // final: confirm step 127 globally, then epoch = 128
        if (w == 0) {
            int spins = 0;
            while (true) {
                u32 f = __hip_atomic_load(&flags[(size_t)(127 * 64 + l) * FLAG_STRIDE],
                                          __ATOMIC_RELAXED, __HIP_MEMORY_SCOPE_SYSTEM);
                if (__ballot(f != 0) == ~0ull) break;
                __builtin_amdgcn_s_sleep(1);
                if (++spins > (1 << 20)) break;
            }
            if (l == 0)
                __hip_atomic_store(&flags[(size_t)(EPOCH_BASE + j) * FLAG_STRIDE], 128u,
                                   __ATOMIC_RELAXED, __HIP_MEMORY_SCOPE_SYSTEM);
        }
        return;
    }

    // ---------------- projection worker ----------------
    // Prologue: cooperative whqt transpose (hidden by n-outer slack). System-scope stores;
    // TCNT counter gates whqt reads.
    {
        float (*tp)[32][33] = (float (*)[32][33])(void*)smem;   // 8448 B
        const int half = tid >> 8, t256 = tid & 255;
        const int r = t256 >> 3, cq = (t256 & 7) * 4;
        const int c = t256 >> 3, rq = (t256 & 7) * 4;
        for (int it = 0; it < 84; ++it) {
            int q = it * 384 + (bx - 64) * 2 + half;
            bool act = q < 32000;
            int rt = 0, ct = 0;
            if (act) { rt = (q / 1000) * 32; ct = (q % 1000) * 32; }
            if (act) {
                float4 v = *(const float4*)(Whq + (size_t)(rt + r) * 32000 + ct + cq);
                tp[half][r][cq] = v.x; tp[half][r][cq + 1] = v.y;
                tp[half][r][cq + 2] = v.z; tp[half][r][cq + 3] = v.w;
            }
            __syncthreads();
            if (act) {
                u64 pk = (u64)f2bf(tp[half][rq][c])
                       | ((u64)f2bf(tp[half][rq + 1][c]) << 16)
                       | ((u64)f2bf(tp[half][rq + 2][c]) << 32)
                       | ((u64)f2bf(tp[half][rq + 3][c]) << 48);
                __hip_atomic_store((u64*)(whqt + (size_t)(ct + c) * 1024 + rt + rq), pk,
                                   __ATOMIC_RELAXED, __HIP_MEMORY_SCOPE_SYSTEM);
            }
            __syncthreads();
        }
        asm volatile("s_waitcnt vmcnt(0)" ::: "memory");
        if (tid == 0)
            __hip_atomic_fetch_add(&flags[(size_t)TCNT_BASE * FLAG_STRIDE], 1u,
                                   __ATOMIC_RELAXED, __HIP_MEMORY_SCOPE_SYSTEM);
    }

    u16* As = (u16*)smem;                   // 2 x 16 KB
    u16* Bs = (u16*)(smem + 32768);         // 2 x 32 KB
    u32* idx_slot = (u32*)(smem + 98304);
    const int wr = w >> 2, wc = w & 3;
    const int lr = l >> 4, lc = l & 15;

    // grab ONE n-tile for the whole run; wait for transpose completion (all 192 blocks)
    if (tid == 0)
        *idx_slot = __hip_atomic_fetch_add(&flags[(size_t)QCNT_BASE * FLAG_STRIDE],
                                           1u, __ATOMIC_RELAXED, __HIP_MEMORY_SCOPE_AGENT);
    if (w == 0) {
        int spins = 0;
        while (__hip_atomic_load(&flags[(size_t)TCNT_BASE * FLAG_STRIDE],
                                 __ATOMIC_RELAXED, __HIP_MEMORY_SCOPE_SYSTEM) < 192u) {
            __builtin_amdgcn_s_sleep(8);
            if (++spins > (1 << 20)) break;
        }
    }
    __syncthreads();
    const u32 myIdx = *idx_slot;
    if (myIdx >= NTILE) return;             // 67 surplus workers exit
    const int n0 = (int)myIdx * 256;

    for (int m = 0; m < 16; ++m) {
        if (w == 0) {                       // wait for t-chunk m readiness (one epoch line)
            const u32 need = (u32)(8 * m + 8);
            int spins = 0;
            while (__hip_atomic_load(&flags[(size_t)(EPOCH_BASE + (bx & 63)) * FLAG_STRIDE],
                                     __ATOMIC_RELAXED, __HIP_MEMORY_SCOPE_SYSTEM) < need) {
                __builtin_amdgcn_s_sleep(8);
                if (++spins > (1 << 20)) break;
            }
        }
        __syncthreads();

        auto STAGE = [&](int bi, int kt) {
#pragma unroll
            for (int i = 0; i < 2; ++i) {           // A: 128 rows x 8 chunks
                int C = i * 512 + tid, r = C >> 3, c = C & 7;
                int sc = c ^ (r & 7);
                int arow = (8 * m + (r & 7)) * 16 + (r >> 3);   // b-major within chunk
                gload_lds16(hs + (size_t)arow * 1024 + kt * 64 + sc * 8,
                            As + (size_t)(bi * 8192 + (i * 512 + w * 64) * 8));
            }
#pragma unroll
            for (int i = 0; i < 4; ++i) {           // B: 256 rows x 8 chunks
                int C = i * 512 + tid, r = C >> 3, c = C & 7;
                int sc = c ^ (r & 7);
                gload_lds16(whqt + (size_t)(n0 + r) * 1024 + kt * 64 + sc * 8,
                            Bs + (size_t)(bi * 16384 + (i * 512 + w * 64) * 8));
            }
        };

        f32x4 acc[4][4];
        f32x4 zz = { 0.f, 0.f, 0.f, 0.f };
#pragma unroll
        for (int i = 0; i < 4; i++)
#pragma unroll
            for (int jj = 0; jj < 4; jj++) acc[i][jj] = zz;

        int cur = 0;
        STAGE(0, 0);
        __syncthreads();
        for (int kt = 0; kt < 16; ++kt) {
            if (kt + 1 < 16) STAGE(cur ^ 1, kt + 1);
            const u16* Ab = As + cur * 8192;
            const u16* Bb = Bs + cur * 16384;
#pragma unroll
            for (int kk = 0; kk < 2; ++kk) {
                bf16x8 af[4], bf[4];
#pragma unroll
                for (int mi = 0; mi < 4; ++mi) {
                    int rA = wr * 64 + mi * 16 + lc;
                    int s = (kk * 4 + lr) ^ (rA & 7);
                    af[mi] = *(const bf16x8*)(Ab + rA * 64 + s * 8);
                }
#pragma unroll
                for (int ni = 0; ni < 4; ++ni) {
                    int rB = wc * 64 + ni * 16 + lc;
                    int s = (kk * 4 + lr) ^ (rB & 7);
                    bf[ni] = *(const bf16x8*)(Bb + rB * 64 + s * 8);
                }
#pragma unroll
                for (int mi = 0; mi < 4; ++mi)
#pragma unroll
                    for (int ni = 0; ni < 4; ++ni)
                        acc[mi][ni] = __builtin_amdgcn_mfma_f32_16x16x32_bf16(af[mi], bf[ni], acc[mi][ni], 0, 0, 0);
            }
            __syncthreads();   // drains vmcnt (next stage landed) + guards buf reuse
            cur ^= 1;
        }
#pragma unroll
        for (int ni = 0; ni < 4; ni++) {
            int col = n0 + wc * 64 + ni * 16 + lc;
            float bv = bq[col];
#pragma unroll
            for (int mi = 0; mi < 4; mi++) {
                int r0 = wr * 64 + mi * 16 + lr * 4;
                int bb = r0 >> 3;
                int t0 = 8 * m + (r0 & 7);
                float4 st = { acc[mi][ni][0] + bv, acc[mi][ni][1] + bv,
                              acc[mi][ni][2] + bv, acc[mi][ni][3] + bv };
                *(float4*)(out + (size_t)bb * 4096000 + (size_t)col * 128 + t0) = st;
            }
        }
    }
}

extern "C" void kernel_launch(void* const* d_in, const int* in_sizes, int n_in,
                              void* d_out, int out_size, void* d_ws, size_t ws_size,
                              hipStream_t stream) {
    const int*   sent = (const int*)d_in[0];
    const float* emb  = (const float*)d_in[1];
    const float* W_i  = (const float*)d_in[2];
    const float* b_i  = (const float*)d_in[3];
    const float* W_f  = (const float*)d_in[4];
    const float* b_f  = (const float*)d_in[5];
    const float* W_o  = (const float*)d_in[6];
    const float* b_o  = (const float*)d_in[7];
    const float* W_c  = (const float*)d_in[8];
    const float* b_c  = (const float*)d_in[9];
    const float* W_hq = (const float*)d_in[10];
    const float* b_q  = (const float*)d_in[11];
    float* out = (float*)d_out;

    char* ws = (char*)d_ws;
    size_t off = 0;
    auto alloc = [&](size_t bytes) { void* p = ws + off; off += (bytes + 255) & ~255ull; return p; };
    u32*   flags = (u32*)alloc((size_t)FLAG_WORDS * 4);
    u16*   xb   = (u16*)alloc((size_t)2048 * 512 * 2);
    u16*   hs   = (u16*)alloc((size_t)2048 * 1024 * 2);
    u16*   whqt = (u16*)alloc((size_t)32000 * 1024 * 2);

    hipMemsetAsync(flags, 0, (size_t)FLAG_WORDS * 4, stream);
    // prep: embedding gather only
    prep<<<1024, 256, 0, stream>>>(sent, emb, xb);
    // fused: 64 lstm blocks (role-split waves) + 192 proj workers
    lstm_proj<<<256, 512, 0, stream>>>(hs, xb, W_i, W_f, W_o, W_c,
                                       b_i, b_f, b_o, b_c,
                                       flags, W_hq, whqt, b_q, out);
}